// Round 1
// baseline (1172.509 us; speedup 1.0000x reference)
//
#include <hip/hip_runtime.h>
#include <math.h>

#define NN    4096      // nodes per graph
#define DF    128       // input feature dim
#define NE    65536     // edges per graph
#define NTOT  8192      // total rows (2 graphs)
#define DP    132       // padded feature dim (130 used + 2 zero)
#define TILE  128
#define KC    44        // K-chunk (3*44 = 132)
#define NTILE 64        // 8192/128
#define NBLK  2080      // 64*65/2 upper-tri tiles
#define R0    16775167u // m/2-1, m = 8192*8191/2 = 33550336
#define R1    16775168u

// ---- workspace layout (bytes) ----
#define OFF_H2A 0ULL                 // u32[1<<20]  4 MB   (zeroed)
#define OFF_H2B 4194304ULL           // u32[1<<20]  4 MB   (zeroed)
#define OFF_MB  8388608ULL           // u32[2][4096*128] 4 MB (zeroed)
#define OFF_H1  12582912ULL          // u32[4096]  16 KB   (zeroed)
#define OFF_DEG 12599296ULL          // int[2][4096] 32 KB (zeroed)
#define OFF_TRI 12632064ULL          // int[2][4096] 32 KB (zeroed)
#define ZERO_BYTES 12664832ULL
#define OFF_XY  12664832ULL          // float[8192*132] 4.33 MB
#define OFF_SQ  16990208ULL          // float[8192]
#define OFF_BS  17022976ULL          // double[2080]
#define OFF_SEL 17039616ULL          // u32[8]
#define OFF_SIG 17039680ULL          // float[1]
#define WS_NEEDED 17039744ULL

// ---------------- build: M bitset + in-degree ----------------
__global__ __launch_bounds__(256) void build_k(const int* __restrict__ eiS, const int* __restrict__ eiT,
                                               unsigned* __restrict__ Mb, int* __restrict__ degc){
  int gid = blockIdx.x*256 + threadIdx.x;      // 0 .. 2*65536-1
  int g = gid >> 16, e = gid & 65535;
  const int* ei = g ? eiT : eiS;
  unsigned* M = Mb + (size_t)g*NN*128;
  int* dg = degc + g*NN;
  int s = ei[e], t = ei[NE + e];
  atomicOr(&M[(size_t)s*128 + (t>>5)], 1u << (t&31));
  atomicAdd(&dg[t], 1);
}

// ---------------- triangles: tri_cnt[i] = sum_e M[i,s]&M[i,t] ----------------
#define GPB 16
__global__ __launch_bounds__(256) void tri_k(const int* __restrict__ eiS, const int* __restrict__ eiT,
                                             const unsigned* __restrict__ Mb, int* __restrict__ tric){
  int g  = blockIdx.x >> 8;
  int nb = blockIdx.x & 255;
  const int* ei = g ? eiT : eiS;
  const unsigned* M = Mb + (size_t)g*NN*128;
  int* tr = tric + g*NN;
  __shared__ unsigned lm[128*20];   // [word][node], stride 20 keeps uint4 16B-aligned
  __shared__ int lcnt[GPB];
  int tid = threadIdx.x;
  for(int idx=tid; idx<128*GPB; idx+=256){
    int w = idx & 127, gg = idx >> 7;
    lm[w*20+gg] = M[(size_t)(nb*GPB+gg)*128 + w];
  }
  if(tid < GPB) lcnt[tid]=0;
  __syncthreads();
  int cnt[GPB];
  #pragma unroll
  for(int q=0;q<GPB;++q) cnt[q]=0;
  for(int e=tid; e<NE; e+=256){
    int s = ei[e], t = ei[NE+e];
    int ws_ = s>>5, bs = s&31, wt = t>>5, bt = t&31;
    const uint4* ps4 = (const uint4*)&lm[ws_*20];
    const uint4* pt4 = (const uint4*)&lm[wt*20];
    unsigned a_[GPB], b_[GPB];
    ((uint4*)a_)[0]=ps4[0]; ((uint4*)a_)[1]=ps4[1]; ((uint4*)a_)[2]=ps4[2]; ((uint4*)a_)[3]=ps4[3];
    ((uint4*)b_)[0]=pt4[0]; ((uint4*)b_)[1]=pt4[1]; ((uint4*)b_)[2]=pt4[2]; ((uint4*)b_)[3]=pt4[3];
    #pragma unroll
    for(int q=0;q<GPB;++q) cnt[q] += (int)((a_[q]>>bs) & (b_[q]>>bt) & 1u);
  }
  #pragma unroll
  for(int q=0;q<GPB;++q){
    int v = cnt[q];
    for(int off=32; off; off>>=1) v += __shfl_down(v, off);
    if((tid&63)==0) atomicAdd(&lcnt[q], v);
  }
  __syncthreads();
  if(tid < GPB) tr[nb*GPB + tid] = lcnt[tid];
}

// ---------------- finalize: struct features -> XY rows + sq norms ----------------
__global__ __launch_bounds__(64) void finalize_k(const float* __restrict__ featS, const float* __restrict__ featT,
                                                 const unsigned* __restrict__ Mb, const int* __restrict__ degc,
                                                 const int* __restrict__ tric, float* __restrict__ XY,
                                                 float* __restrict__ sq){
  int b = blockIdx.x;              // 0..8191
  int g = b >> 12, i = b & 4095;
  int lane = threadIdx.x;          // 64
  const unsigned* Mr = Mb + (size_t)g*NN*128 + (size_t)i*128;
  int pc = __popc(Mr[lane]) + __popc(Mr[64+lane]);
  for(int off=32; off; off>>=1) pc += __shfl_down(pc, off);
  pc = __shfl(pc, 0);
  const float* feats = g ? featT : featS;
  float* row = XY + (size_t)(g*NN + i)*DP;
  float v0 = feats[(size_t)i*DF + lane];
  float v1 = feats[(size_t)i*DF + 64 + lane];
  row[lane] = v0; row[64+lane] = v1;
  float s0 = v0*v0 + v1*v1;
  if(lane==0){
    float degf = (float)degc[g*NN+i];
    float nd   = degf / 4095.0f;                 // deg/(n-1)
    float dd   = (float)pc;
    float tri  = 0.5f * (float)tric[g*NN+i];
    float me   = dd*(dd-1.0f)*0.5f;
    float cl   = (dd >= 2.0f) ? (tri / fmaxf(me, 1.0f)) : 0.0f;
    float f0 = 0.1f * nd;
    float f1 = 0.1f * log1pf(cl);
    row[128]=f0; row[129]=f1; row[130]=0.0f; row[131]=0.0f;
    s0 += f0*f0 + f1*f1;
  }
  for(int off=32; off; off>>=1) s0 += __shfl_down(s0, off);
  if(lane==0) sq[g*NN+i] = s0;
}

// ---------------- pairwise passes: MODE 0 hist12, 1 hist20, 2 kernel-sums ----------------
template<int MODE>
__global__ __launch_bounds__(256) void pair_k(const float* __restrict__ XY, const float* __restrict__ sq,
                                              unsigned* __restrict__ hist1, unsigned* __restrict__ h2a,
                                              unsigned* __restrict__ h2b, const unsigned* __restrict__ sel,
                                              const float* __restrict__ sigp, double* __restrict__ blockSums){
  int t = blockIdx.x, bi = 0;
  while(t >= NTILE - bi){ t -= NTILE - bi; ++bi; }
  int bj = bi + t;                              // bi <= bj, upper-tri tile
  __shared__ float As[KC][TILE];
  __shared__ float Bs[KC][TILE];
  int tid = threadIdx.x;
  int trw = tid >> 4, tcl = tid & 15;
  float acc[8][8];
  #pragma unroll
  for(int r=0;r<8;++r){
    #pragma unroll
    for(int c=0;c<8;++c) acc[r][c]=0.f;
  }
  int i0 = bi*TILE, j0 = bj*TILE;
  for(int kc=0; kc<3; ++kc){
    for(int idx=tid; idx<TILE*11; idx+=256){
      int r = idx/11, q = idx - r*11;
      float4 va = *(const float4*)&XY[(size_t)(i0+r)*DP + kc*KC + q*4];
      float4 vb = *(const float4*)&XY[(size_t)(j0+r)*DP + kc*KC + q*4];
      int k = q*4;
      As[k][r]=va.x; As[k+1][r]=va.y; As[k+2][r]=va.z; As[k+3][r]=va.w;
      Bs[k][r]=vb.x; Bs[k+1][r]=vb.y; Bs[k+2][r]=vb.z; Bs[k+3][r]=vb.w;
    }
    __syncthreads();
    #pragma unroll 4
    for(int k=0;k<KC;++k){
      float a[8], b[8];
      *(float4*)&a[0] = *(const float4*)&As[k][trw*8];
      *(float4*)&a[4] = *(const float4*)&As[k][trw*8+4];
      *(float4*)&b[0] = *(const float4*)&Bs[k][tcl*8];
      *(float4*)&b[4] = *(const float4*)&Bs[k][tcl*8+4];
      #pragma unroll
      for(int r=0;r<8;++r){
        #pragma unroll
        for(int c=0;c<8;++c) acc[r][c] = fmaf(a[r], b[c], acc[r][c]);
      }
    }
    __syncthreads();
  }
  float sqi[8], sqj[8];
  #pragma unroll
  for(int r=0;r<8;++r) sqi[r] = sq[i0 + trw*8 + r];
  #pragma unroll
  for(int c=0;c<8;++c) sqj[c] = sq[j0 + tcl*8 + c];

  if constexpr (MODE==0){
    __shared__ unsigned lh[4096];
    for(int x=tid;x<4096;x+=256) lh[x]=0u;
    __syncthreads();
    #pragma unroll
    for(int r=0;r<8;++r){
      #pragma unroll
      for(int c=0;c<8;++c){
        int i = i0 + trw*8 + r, j = j0 + tcl*8 + c;
        if(bi!=bj || i<j){
          float d = fmaxf(sqi[r]+sqj[c]-2.0f*acc[r][c], 0.0f);
          atomicAdd(&lh[__float_as_uint(d)>>20], 1u);
        }
      }
    }
    __syncthreads();
    for(int x=tid;x<4096;x+=256){ unsigned v=lh[x]; if(v) atomicAdd(&hist1[x], v); }
  } else if constexpr (MODE==1){
    unsigned b0 = sel[0], b1 = sel[1];
    #pragma unroll
    for(int r=0;r<8;++r){
      #pragma unroll
      for(int c=0;c<8;++c){
        int i = i0 + trw*8 + r, j = j0 + tcl*8 + c;
        if(bi!=bj || i<j){
          float d = fmaxf(sqi[r]+sqj[c]-2.0f*acc[r][c], 0.0f);
          unsigned bits = __float_as_uint(d);
          unsigned top = bits >> 20;
          if(top==b0)      atomicAdd(&h2a[bits & 0xFFFFFu], 1u);
          else if(top==b1) atomicAdd(&h2b[bits & 0xFFFFFu], 1u);
        }
      }
    }
  } else {
    float sig = *sigp;
    float inv = 1.0f/sig;
    // args: -d/(2*bw_i), bw_i = sig*2^(i-2), i=0..4
    float k0=2.0f*inv, k1=inv, k2=0.5f*inv, k3=0.25f*inv, k4=0.125f*inv;
    double lsum = 0.0;
    #pragma unroll
    for(int r=0;r<8;++r){
      #pragma unroll
      for(int c=0;c<8;++c){
        int i = i0 + trw*8 + r, j = j0 + tcl*8 + c;
        if(bi!=bj || i<j){
          float d = fmaxf(sqi[r]+sqj[c]-2.0f*acc[r][c], 0.0f);
          float kv = expf(-d*k0)+expf(-d*k1)+expf(-d*k2)+expf(-d*k3)+expf(-d*k4);
          lsum += (double)kv;
        }
      }
    }
    for(int off=32; off; off>>=1) lsum += __shfl_down(lsum, off);
    __shared__ double redbuf[4];
    if((tid&63)==0) redbuf[tid>>6] = lsum;
    __syncthreads();
    if(tid==0) blockSums[blockIdx.x] = (redbuf[0]+redbuf[1]+redbuf[2]+redbuf[3])*0.2; // /KERNEL_NUM
  }
}

// ---------------- selection 1: find 12-bit bucket + in-bucket ranks ----------------
__global__ __launch_bounds__(256) void sel1_k(const unsigned* __restrict__ hist1, unsigned* __restrict__ sel){
  __shared__ unsigned part[256];
  int tid = threadIdx.x;
  unsigned s = 0;
  #pragma unroll
  for(int k=0;k<16;++k) s += hist1[tid*16+k];
  part[tid] = s;
  __syncthreads();
  if(tid==0){
    const unsigned ranks[2] = {R0, R1};
    unsigned segs[2], bases[2];
    unsigned cum = 0; int found = 0;
    for(int i=0; i<256 && found<2; ++i){
      unsigned nx = cum + part[i];
      while(found<2 && ranks[found] < nx){ segs[found]=i; bases[found]=cum; ++found; }
      cum = nx;
    }
    for(int tg=0; tg<2; ++tg){
      unsigned c2 = bases[tg];
      for(int b=segs[tg]*16;; ++b){
        unsigned nx = c2 + hist1[b];
        if(ranks[tg] < nx){ sel[tg]=(unsigned)b; sel[2+tg]=ranks[tg]-c2; break; }
        c2 = nx;
      }
    }
  }
}

// ---------------- selection 2: exact order statistics -> sigma ----------------
__global__ __launch_bounds__(1024) void sel2_k(const unsigned* __restrict__ h2a, const unsigned* __restrict__ h2b,
                                               const unsigned* __restrict__ sel, float* __restrict__ sigp){
  __shared__ unsigned part[1024];
  __shared__ unsigned segbins[1024];
  __shared__ unsigned sres[2];
  __shared__ unsigned outbits[2];
  int tid = threadIdx.x;
  for(int tgt=0; tgt<2; ++tgt){
    unsigned bucket = sel[tgt];
    unsigned rank   = sel[2+tgt];
    const unsigned* H = (tgt==0) ? h2a : ((sel[1]==sel[0]) ? h2a : h2b);
    const uint4* H4 = (const uint4*)(H + (size_t)tid*1024);
    unsigned s = 0;
    for(int k=0;k<256;++k){ uint4 v = H4[k]; s += v.x+v.y+v.z+v.w; }
    part[tid] = s;
    __syncthreads();
    if(tid==0){
      unsigned cum=0, base=0; int seg=-1;
      for(int i=0;i<1024;++i){ unsigned nx=cum+part[i]; if(seg<0 && rank<nx){seg=i; base=cum;} cum=nx; }
      sres[0]=(unsigned)seg; sres[1]=base;
    }
    __syncthreads();
    unsigned seg = sres[0], base = sres[1];
    segbins[tid] = H[(size_t)seg*1024 + tid];
    __syncthreads();
    if(tid==0){
      unsigned cum = base;
      unsigned bin = 0;
      for(int i=0;i<1024;++i){ unsigned nx=cum+segbins[i]; if(rank<nx){bin=(unsigned)i; break;} cum=nx; }
      outbits[tgt] = (bucket<<20) | (seg<<10) | bin;
    }
    __syncthreads();
  }
  if(tid==0){
    float v0 = __uint_as_float(outbits[0]);
    float v1 = __uint_as_float(outbits[1]);
    *sigp = 0.5f*(v0+v1);
  }
}

// ---------------- final reduction: MMD ----------------
__global__ __launch_bounds__(256) void final_k(const double* __restrict__ blockSums, float* __restrict__ out){
  __shared__ double cls[3][256];
  int tid = threadIdx.x;
  double l0=0, l1=0, l2=0;
  for(int b=tid; b<NBLK; b+=256){
    int t=b, bi=0;
    while(t >= NTILE - bi){ t -= NTILE - bi; ++bi; }
    int bj = bi + t;
    double v = blockSums[b];
    if(bj < 32) l0 += v;          // XX (rows 0..4095 are tiles 0..31)
    else if(bi >= 32) l2 += v;    // YY
    else l1 += v;                 // XY
  }
  cls[0][tid]=l0; cls[1][tid]=l1; cls[2][tid]=l2;
  __syncthreads();
  for(int off=128; off; off>>=1){
    if(tid<off){ cls[0][tid]+=cls[0][tid+off]; cls[1][tid]+=cls[1][tid+off]; cls[2][tid]+=cls[2][tid+off]; }
    __syncthreads();
  }
  if(tid==0){
    double sxx=cls[0][0], sxy=cls[1][0], syy=cls[2][0];
    double mxx = (2.0*sxx)/((double)NN*(NN-1));   // trace cancels: K(0)=1 per row
    double myy = (2.0*syy)/((double)NN*(NN-1));
    double mxy = sxy/((double)NN*(double)NN);
    double r = mxx + myy - 2.0*mxy;
    out[0] = fmaxf((float)r, 0.0f);
  }
}

extern "C" void kernel_launch(void* const* d_in, const int* in_sizes, int n_in,
                              void* d_out, int out_size, void* d_ws, size_t ws_size,
                              hipStream_t stream){
  (void)in_sizes; (void)n_in; (void)out_size; (void)ws_size;
  const float* featS = (const float*)d_in[0];
  const float* featT = (const float*)d_in[1];
  const int*   eiS   = (const int*)d_in[2];
  const int*   eiT   = (const int*)d_in[3];
  char* ws = (char*)d_ws;
  unsigned* h2a   = (unsigned*)(ws + OFF_H2A);
  unsigned* h2b   = (unsigned*)(ws + OFF_H2B);
  unsigned* Mb    = (unsigned*)(ws + OFF_MB);
  unsigned* hist1 = (unsigned*)(ws + OFF_H1);
  int*      degc  = (int*)(ws + OFF_DEG);
  int*      tric  = (int*)(ws + OFF_TRI);
  float*    XY    = (float*)(ws + OFF_XY);
  float*    sq    = (float*)(ws + OFF_SQ);
  double*   bsums = (double*)(ws + OFF_BS);
  unsigned* sel   = (unsigned*)(ws + OFF_SEL);
  float*    sigp  = (float*)(ws + OFF_SIG);
  float*    out   = (float*)d_out;

  hipMemsetAsync(ws, 0, (size_t)ZERO_BYTES, stream);

  build_k   <<<512, 256, 0, stream>>>(eiS, eiT, Mb, degc);
  tri_k     <<<512, 256, 0, stream>>>(eiS, eiT, Mb, tric);
  finalize_k<<<NTOT, 64, 0, stream>>>(featS, featT, Mb, degc, tric, XY, sq);

  pair_k<0><<<NBLK, 256, 0, stream>>>(XY, sq, hist1, h2a, h2b, sel, sigp, bsums);
  sel1_k   <<<1, 256, 0, stream>>>(hist1, sel);
  pair_k<1><<<NBLK, 256, 0, stream>>>(XY, sq, hist1, h2a, h2b, sel, sigp, bsums);
  sel2_k   <<<1, 1024, 0, stream>>>(h2a, h2b, sel, sigp);
  pair_k<2><<<NBLK, 256, 0, stream>>>(XY, sq, hist1, h2a, h2b, sel, sigp, bsums);

  final_k  <<<1, 256, 0, stream>>>(bsums, out);
}

// Round 3
// 736.087 us; speedup vs baseline: 1.5929x; 1.5929x over previous
//
#include <hip/hip_runtime.h>
#include <math.h>

#define NN    4096      // nodes per graph
#define DF    128       // input feature dim
#define NE    65536     // edges per graph
#define NTOT  8192      // total rows (2 graphs)
#define DP    132       // padded feature dim (130 used + 2 zero)
#define TILE  128
#define KC    44        // K-chunk (3*44 = 132)
#define NTILE 64        // 8192/128
#define NBLK  2080      // 64*65/2 upper-tri tiles
#define R0    16775167u // m/2-1, m = 8192*8191/2 = 33550336
#define R1    16775168u
#define FINF  __int_as_float(0x7f800000)

// ---- workspace layout (bytes) ----
#define OFF_H2A 0ULL                 // u32[1<<20]  4 MB   (zeroed)
#define OFF_H2B 4194304ULL           // u32[1<<20]  4 MB   (zeroed)
#define OFF_MB  8388608ULL           // u32[2][4096*128] 4 MB (zeroed)
#define OFF_H1  12582912ULL          // u32[4096]  16 KB   (zeroed)
#define OFF_DEG 12599296ULL          // int[2][4096] 32 KB (zeroed)
#define OFF_TRI 12632064ULL          // int[2][4096] 32 KB (zeroed)
#define ZERO_BYTES 12664832ULL
#define OFF_XY  12664832ULL          // float[8192*132] 4.33 MB
#define OFF_SQ  16990208ULL          // float[8192]
#define OFF_BS  17022976ULL          // double[2080]
#define OFF_SEL 17039616ULL          // u32[8]
#define OFF_SIG 17039680ULL          // float[1]
#define OFF_PART 17039744ULL         // u32[2048] partial sums for sel2 scan
#define OFF_D   17047936ULL          // float[2080*16384] = 136,314,880 B (cached-distance path)
#define DBYTES  136314880ULL
#define WS_CACHED (OFF_D + DBYTES)   // 153,362,816

// ---------------- build: M bitset + in-degree ----------------
__global__ __launch_bounds__(256) void build_k(const int* __restrict__ eiS, const int* __restrict__ eiT,
                                               unsigned* __restrict__ Mb, int* __restrict__ degc){
  int gid = blockIdx.x*256 + threadIdx.x;      // 0 .. 2*65536-1
  int g = gid >> 16, e = gid & 65535;
  const int* ei = g ? eiT : eiS;
  unsigned* M = Mb + (size_t)g*NN*128;
  int* dg = degc + g*NN;
  int s = ei[e], t = ei[NE + e];
  atomicOr(&M[(size_t)s*128 + (t>>5)], 1u << (t&31));
  atomicAdd(&dg[t], 1);
}

// ---------------- triangles: tri_cnt[i] = sum_e M[i,s]&M[i,t] ----------------
#define GPB 16
__global__ __launch_bounds__(256) void tri_k(const int* __restrict__ eiS, const int* __restrict__ eiT,
                                             const unsigned* __restrict__ Mb, int* __restrict__ tric){
  int g  = blockIdx.x >> 8;
  int nb = blockIdx.x & 255;
  const int* ei = g ? eiT : eiS;
  const unsigned* M = Mb + (size_t)g*NN*128;
  int* tr = tric + g*NN;
  __shared__ unsigned lm[128*20];   // [word][node], stride 20 keeps uint4 16B-aligned
  __shared__ int lcnt[GPB];
  int tid = threadIdx.x;
  for(int idx=tid; idx<128*GPB; idx+=256){
    int w = idx & 127, gg = idx >> 7;
    lm[w*20+gg] = M[(size_t)(nb*GPB+gg)*128 + w];
  }
  if(tid < GPB) lcnt[tid]=0;
  __syncthreads();
  int cnt[GPB];
  #pragma unroll
  for(int q=0;q<GPB;++q) cnt[q]=0;
  for(int e=tid; e<NE; e+=256){
    int s = ei[e], t = ei[NE+e];
    int ws_ = s>>5, bs = s&31, wt = t>>5, bt = t&31;
    const uint4* ps4 = (const uint4*)&lm[ws_*20];
    const uint4* pt4 = (const uint4*)&lm[wt*20];
    unsigned a_[GPB], b_[GPB];
    ((uint4*)a_)[0]=ps4[0]; ((uint4*)a_)[1]=ps4[1]; ((uint4*)a_)[2]=ps4[2]; ((uint4*)a_)[3]=ps4[3];
    ((uint4*)b_)[0]=pt4[0]; ((uint4*)b_)[1]=pt4[1]; ((uint4*)b_)[2]=pt4[2]; ((uint4*)b_)[3]=pt4[3];
    #pragma unroll
    for(int q=0;q<GPB;++q) cnt[q] += (int)((a_[q]>>bs) & (b_[q]>>bt) & 1u);
  }
  #pragma unroll
  for(int q=0;q<GPB;++q){
    int v = cnt[q];
    for(int off=32; off; off>>=1) v += __shfl_down(v, off);
    if((tid&63)==0) atomicAdd(&lcnt[q], v);
  }
  __syncthreads();
  if(tid < GPB) tr[nb*GPB + tid] = lcnt[tid];
}

// ---------------- finalize: struct features -> XY rows + sq norms ----------------
__global__ __launch_bounds__(64) void finalize_k(const float* __restrict__ featS, const float* __restrict__ featT,
                                                 const unsigned* __restrict__ Mb, const int* __restrict__ degc,
                                                 const int* __restrict__ tric, float* __restrict__ XY,
                                                 float* __restrict__ sq){
  int b = blockIdx.x;              // 0..8191
  int g = b >> 12, i = b & 4095;
  int lane = threadIdx.x;          // 64
  const unsigned* Mr = Mb + (size_t)g*NN*128 + (size_t)i*128;
  int pc = __popc(Mr[lane]) + __popc(Mr[64+lane]);
  for(int off=32; off; off>>=1) pc += __shfl_down(pc, off);
  pc = __shfl(pc, 0);
  const float* feats = g ? featT : featS;
  float* row = XY + (size_t)(g*NN + i)*DP;
  float v0 = feats[(size_t)i*DF + lane];
  float v1 = feats[(size_t)i*DF + 64 + lane];
  row[lane] = v0; row[64+lane] = v1;
  float s0 = v0*v0 + v1*v1;
  if(lane==0){
    float degf = (float)degc[g*NN+i];
    float nd   = degf / 4095.0f;                 // deg/(n-1)
    float dd   = (float)pc;
    float tri  = 0.5f * (float)tric[g*NN+i];
    float me   = dd*(dd-1.0f)*0.5f;
    float cl   = (dd >= 2.0f) ? (tri / fmaxf(me, 1.0f)) : 0.0f;
    float f0 = 0.1f * nd;
    float f1 = 0.1f * log1pf(cl);
    row[128]=f0; row[129]=f1; row[130]=0.0f; row[131]=0.0f;
    s0 += f0*f0 + f1*f1;
  }
  for(int off=32; off; off>>=1) s0 += __shfl_down(s0, off);
  if(lane==0) sq[g*NN+i] = s0;
}

// ---------------- pairwise passes ----------------
// MODE 0: hist12 only (fallback)   MODE 3: hist12 + store distances
// MODE 1: hist20 recompute (fallback)   MODE 2: kernel sums recompute (fallback)
template<int MODE>
__global__ __launch_bounds__(256) void pair_k(const float* __restrict__ XY, const float* __restrict__ sq,
                                              unsigned* __restrict__ hist1, unsigned* __restrict__ h2a,
                                              unsigned* __restrict__ h2b, const unsigned* __restrict__ sel,
                                              const float* __restrict__ sigp, double* __restrict__ blockSums,
                                              float* __restrict__ Dout){
  int t = blockIdx.x, bi = 0;
  while(t >= NTILE - bi){ t -= NTILE - bi; ++bi; }
  int bj = bi + t;                              // bi <= bj, upper-tri tile
  __shared__ float As[KC][TILE];
  __shared__ float Bs[KC][TILE];
  int tid = threadIdx.x;
  int trw = tid >> 4, tcl = tid & 15;
  float acc[8][8];
  #pragma unroll
  for(int r=0;r<8;++r){
    #pragma unroll
    for(int c=0;c<8;++c) acc[r][c]=0.f;
  }
  int i0 = bi*TILE, j0 = bj*TILE;
  for(int kc=0; kc<3; ++kc){
    for(int idx=tid; idx<TILE*11; idx+=256){
      int r = idx/11, q = idx - r*11;
      float4 va = *(const float4*)&XY[(size_t)(i0+r)*DP + kc*KC + q*4];
      float4 vb = *(const float4*)&XY[(size_t)(j0+r)*DP + kc*KC + q*4];
      int k = q*4;
      As[k][r]=va.x; As[k+1][r]=va.y; As[k+2][r]=va.z; As[k+3][r]=va.w;
      Bs[k][r]=vb.x; Bs[k+1][r]=vb.y; Bs[k+2][r]=vb.z; Bs[k+3][r]=vb.w;
    }
    __syncthreads();
    #pragma unroll 4
    for(int k=0;k<KC;++k){
      float a[8], b[8];
      *(float4*)&a[0] = *(const float4*)&As[k][trw*8];
      *(float4*)&a[4] = *(const float4*)&As[k][trw*8+4];
      *(float4*)&b[0] = *(const float4*)&Bs[k][tcl*8];
      *(float4*)&b[4] = *(const float4*)&Bs[k][tcl*8+4];
      #pragma unroll
      for(int r=0;r<8;++r){
        #pragma unroll
        for(int c=0;c<8;++c) acc[r][c] = fmaf(a[r], b[c], acc[r][c]);
      }
    }
    __syncthreads();
  }
  float sqi[8], sqj[8];
  #pragma unroll
  for(int r=0;r<8;++r) sqi[r] = sq[i0 + trw*8 + r];
  #pragma unroll
  for(int c=0;c<8;++c) sqj[c] = sq[j0 + tcl*8 + c];

  if constexpr (MODE==0 || MODE==3){
    __shared__ unsigned lh[4096];
    for(int x=tid;x<4096;x+=256) lh[x]=0u;
    __syncthreads();
    #pragma unroll
    for(int r=0;r<8;++r){
      float rowd[8];
      #pragma unroll
      for(int c=0;c<8;++c){
        int i = i0 + trw*8 + r, j = j0 + tcl*8 + c;
        bool valid = (bi!=bj) || (i<j);
        float d = fmaxf(sqi[r]+sqj[c]-2.0f*acc[r][c], 0.0f);
        rowd[c] = valid ? d : FINF;
        if(valid) atomicAdd(&lh[__float_as_uint(d)>>20], 1u);
      }
      if constexpr (MODE==3){
        float* rp = Dout + (size_t)blockIdx.x*16384 + (size_t)(trw*8+r)*128 + tcl*8;
        *(float4*)rp       = make_float4(rowd[0],rowd[1],rowd[2],rowd[3]);
        *(float4*)(rp+4)   = make_float4(rowd[4],rowd[5],rowd[6],rowd[7]);
      }
    }
    __syncthreads();
    for(int x=tid;x<4096;x+=256){ unsigned v=lh[x]; if(v) atomicAdd(&hist1[x], v); }
  } else if constexpr (MODE==1){
    unsigned b0 = sel[0], b1 = sel[1];
    #pragma unroll
    for(int r=0;r<8;++r){
      #pragma unroll
      for(int c=0;c<8;++c){
        int i = i0 + trw*8 + r, j = j0 + tcl*8 + c;
        if(bi!=bj || i<j){
          float d = fmaxf(sqi[r]+sqj[c]-2.0f*acc[r][c], 0.0f);
          unsigned bits = __float_as_uint(d);
          unsigned top = bits >> 20;
          if(top==b0)      atomicAdd(&h2a[bits & 0xFFFFFu], 1u);
          else if(top==b1) atomicAdd(&h2b[bits & 0xFFFFFu], 1u);
        }
      }
    }
  } else {
    float sig = *sigp;
    float inv = 1.0f/sig;
    float k0=2.0f*inv, k1=inv, k2=0.5f*inv, k3=0.25f*inv, k4=0.125f*inv;
    double lsum = 0.0;
    #pragma unroll
    for(int r=0;r<8;++r){
      #pragma unroll
      for(int c=0;c<8;++c){
        int i = i0 + trw*8 + r, j = j0 + tcl*8 + c;
        if(bi!=bj || i<j){
          float d = fmaxf(sqi[r]+sqj[c]-2.0f*acc[r][c], 0.0f);
          float kv = expf(-d*k0)+expf(-d*k1)+expf(-d*k2)+expf(-d*k3)+expf(-d*k4);
          lsum += (double)kv;
        }
      }
    }
    for(int off=32; off; off>>=1) lsum += __shfl_down(lsum, off);
    __shared__ double redbuf[4];
    if((tid&63)==0) redbuf[tid>>6] = lsum;
    __syncthreads();
    if(tid==0) blockSums[blockIdx.x] = (redbuf[0]+redbuf[1]+redbuf[2]+redbuf[3])*0.2; // /KERNEL_NUM
  }
}

// ---------------- streaming hist20 over cached distances ----------------
__global__ __launch_bounds__(256) void hist2s_k(const float* __restrict__ D, const unsigned* __restrict__ sel,
                                                unsigned* __restrict__ h2a, unsigned* __restrict__ h2b){
  unsigned b0 = sel[0], b1 = sel[1];
  const float4* P = (const float4*)(D + (size_t)blockIdx.x*16384);
  int tid = threadIdx.x;
  #pragma unroll
  for(int k=0;k<16;++k){
    float4 v = P[tid + k*256];
    float vals[4] = {v.x, v.y, v.z, v.w};
    #pragma unroll
    for(int q=0;q<4;++q){
      unsigned bits = __float_as_uint(vals[q]);
      unsigned top = bits >> 20;           // +inf sentinel (0x7F8) never matches a finite bucket
      if(top==b0)      atomicAdd(&h2a[bits & 0xFFFFFu], 1u);
      else if(top==b1) atomicAdd(&h2b[bits & 0xFFFFFu], 1u);
    }
  }
}

// ---------------- streaming kernel sums over cached distances ----------------
__global__ __launch_bounds__(256) void ksum_k(const float* __restrict__ D, const float* __restrict__ sigp,
                                              double* __restrict__ blockSums){
  float sig = *sigp;
  float inv = 1.0f/sig;
  float k0=2.0f*inv, k1=inv, k2=0.5f*inv, k3=0.25f*inv, k4=0.125f*inv;
  const float4* P = (const float4*)(D + (size_t)blockIdx.x*16384);
  int tid = threadIdx.x;
  double lsum = 0.0;
  #pragma unroll
  for(int k=0;k<16;++k){
    float4 v = P[tid + k*256];
    float vals[4] = {v.x, v.y, v.z, v.w};
    #pragma unroll
    for(int q=0;q<4;++q){
      float d = vals[q];                   // +inf sentinel -> expf(-inf)=0 contributes nothing
      float kv = expf(-d*k0)+expf(-d*k1)+expf(-d*k2)+expf(-d*k3)+expf(-d*k4);
      lsum += (double)kv;
    }
  }
  for(int off=32; off; off>>=1) lsum += __shfl_down(lsum, off);
  __shared__ double redbuf[4];
  if((tid&63)==0) redbuf[tid>>6] = lsum;
  __syncthreads();
  if(tid==0) blockSums[blockIdx.x] = (redbuf[0]+redbuf[1]+redbuf[2]+redbuf[3])*0.2;
}

// ---------------- selection 1: find 12-bit bucket + in-bucket ranks ----------------
__global__ __launch_bounds__(256) void sel1_k(const unsigned* __restrict__ hist1, unsigned* __restrict__ sel){
  __shared__ unsigned part[256];
  int tid = threadIdx.x;
  unsigned s = 0;
  #pragma unroll
  for(int k=0;k<16;++k) s += hist1[tid*16+k];
  part[tid] = s;
  __syncthreads();
  if(tid==0){
    const unsigned ranks[2] = {R0, R1};
    unsigned segs[2], bases[2];
    unsigned cum = 0; int found = 0;
    for(int i=0; i<256 && found<2; ++i){
      unsigned nx = cum + part[i];
      while(found<2 && ranks[found] < nx){ segs[found]=i; bases[found]=cum; ++found; }
      cum = nx;
    }
    for(int tg=0; tg<2; ++tg){
      unsigned c2 = bases[tg];
      for(int b=segs[tg]*16;; ++b){
        unsigned nx = c2 + hist1[b];
        if(ranks[tg] < nx){ sel[tg]=(unsigned)b; sel[2+tg]=ranks[tg]-c2; break; }
        c2 = nx;
      }
    }
  }
}

// ---------------- selection 2a: parallel partial sums over h2a/h2b ----------------
__global__ __launch_bounds__(256) void sel2a_k(const unsigned* __restrict__ h2a, const unsigned* __restrict__ h2b,
                                               unsigned* __restrict__ part){
  int b = blockIdx.x;                 // 0..2047: 0..1023 -> h2a segs, 1024..2047 -> h2b segs
  const unsigned* H = (b < 1024) ? h2a : h2b;
  int seg = b & 1023;
  int tid = threadIdx.x;
  const uint4* H4 = (const uint4*)(H + (size_t)seg*1024);
  uint4 v = H4[tid];
  unsigned s = v.x + v.y + v.z + v.w;
  for(int off=32; off; off>>=1) s += __shfl_down(s, off);
  __shared__ unsigned red[4];
  if((tid&63)==0) red[tid>>6] = s;
  __syncthreads();
  if(tid==0) part[b] = red[0]+red[1]+red[2]+red[3];
}

// ---------------- selection 2b: scan partials + drill into segment -> sigma ----------------
__global__ __launch_bounds__(1024) void sel2b_k(const unsigned* __restrict__ part,
                                                const unsigned* __restrict__ h2a, const unsigned* __restrict__ h2b,
                                                const unsigned* __restrict__ sel, float* __restrict__ sigp){
  __shared__ unsigned buf[1024];
  __shared__ unsigned segres[2];     // seg, base
  __shared__ unsigned outbits[2];
  int tid = threadIdx.x;
  for(int tgt=0; tgt<2; ++tgt){
    bool useA = (tgt==0) || (sel[1]==sel[0]);
    const unsigned* H = useA ? h2a : h2b;
    const unsigned* P = part + (useA ? 0 : 1024);
    unsigned rank = sel[2+tgt];
    // inclusive scan of partials
    buf[tid] = P[tid];
    __syncthreads();
    for(int off=1; off<1024; off<<=1){
      unsigned v = buf[tid];
      unsigned add = (tid>=off) ? buf[tid-off] : 0u;
      __syncthreads();
      buf[tid] = v + add;
      __syncthreads();
    }
    unsigned prev = tid ? buf[tid-1] : 0u;
    if(rank < buf[tid] && rank >= prev){ segres[0]=(unsigned)tid; segres[1]=prev; }
    __syncthreads();
    unsigned seg = segres[0], base = segres[1];
    // inclusive scan of the segment's 1024 bins
    buf[tid] = H[(size_t)seg*1024 + tid];
    __syncthreads();
    for(int off=1; off<1024; off<<=1){
      unsigned v = buf[tid];
      unsigned add = (tid>=off) ? buf[tid-off] : 0u;
      __syncthreads();
      buf[tid] = v + add;
      __syncthreads();
    }
    unsigned r2 = rank - base;
    prev = tid ? buf[tid-1] : 0u;
    if(r2 < buf[tid] && r2 >= prev){
      outbits[tgt] = (sel[tgt]<<20) | (seg<<10) | (unsigned)tid;
    }
    __syncthreads();
  }
  if(tid==0){
    float v0 = __uint_as_float(outbits[0]);
    float v1 = __uint_as_float(outbits[1]);
    *sigp = 0.5f*(v0+v1);
  }
}

// ---------------- final reduction: MMD ----------------
__global__ __launch_bounds__(256) void final_k(const double* __restrict__ blockSums, float* __restrict__ out){
  __shared__ double cls[3][256];
  int tid = threadIdx.x;
  double l0=0, l1=0, l2=0;
  for(int b=tid; b<NBLK; b+=256){
    int t=b, bi=0;
    while(t >= NTILE - bi){ t -= NTILE - bi; ++bi; }
    int bj = bi + t;
    double v = blockSums[b];
    if(bj < 32) l0 += v;          // XX
    else if(bi >= 32) l2 += v;    // YY
    else l1 += v;                 // XY
  }
  cls[0][tid]=l0; cls[1][tid]=l1; cls[2][tid]=l2;
  __syncthreads();
  for(int off=128; off; off>>=1){
    if(tid<off){ cls[0][tid]+=cls[0][tid+off]; cls[1][tid]+=cls[1][tid+off]; cls[2][tid]+=cls[2][tid+off]; }
    __syncthreads();
  }
  if(tid==0){
    double sxx=cls[0][0], sxy=cls[1][0], syy=cls[2][0];
    double mxx = (2.0*sxx)/((double)NN*(NN-1));   // trace cancels: K(0)=1 per row
    double myy = (2.0*syy)/((double)NN*(NN-1));
    double mxy = sxy/((double)NN*(double)NN);
    double r = mxx + myy - 2.0*mxy;
    out[0] = fmaxf((float)r, 0.0f);
  }
}

extern "C" void kernel_launch(void* const* d_in, const int* in_sizes, int n_in,
                              void* d_out, int out_size, void* d_ws, size_t ws_size,
                              hipStream_t stream){
  (void)in_sizes; (void)n_in; (void)out_size;
  const float* featS = (const float*)d_in[0];
  const float* featT = (const float*)d_in[1];
  const int*   eiS   = (const int*)d_in[2];
  const int*   eiT   = (const int*)d_in[3];
  char* ws = (char*)d_ws;
  unsigned* h2a   = (unsigned*)(ws + OFF_H2A);
  unsigned* h2b   = (unsigned*)(ws + OFF_H2B);
  unsigned* Mb    = (unsigned*)(ws + OFF_MB);
  unsigned* hist1 = (unsigned*)(ws + OFF_H1);
  int*      degc  = (int*)(ws + OFF_DEG);
  int*      tric  = (int*)(ws + OFF_TRI);
  float*    XY    = (float*)(ws + OFF_XY);
  float*    sq    = (float*)(ws + OFF_SQ);
  double*   bsums = (double*)(ws + OFF_BS);
  unsigned* sel   = (unsigned*)(ws + OFF_SEL);
  float*    sigp  = (float*)(ws + OFF_SIG);
  unsigned* part  = (unsigned*)(ws + OFF_PART);
  float*    Dbuf  = (float*)(ws + OFF_D);
  float*    out   = (float*)d_out;

  const bool cached = (ws_size >= WS_CACHED);   // launch-constant -> graph-capture safe

  hipMemsetAsync(ws, 0, (size_t)ZERO_BYTES, stream);

  build_k   <<<512, 256, 0, stream>>>(eiS, eiT, Mb, degc);
  tri_k     <<<512, 256, 0, stream>>>(eiS, eiT, Mb, tric);
  finalize_k<<<NTOT, 64, 0, stream>>>(featS, featT, Mb, degc, tric, XY, sq);

  if(cached){
    pair_k<3><<<NBLK, 256, 0, stream>>>(XY, sq, hist1, h2a, h2b, sel, sigp, bsums, Dbuf);
    sel1_k   <<<1, 256, 0, stream>>>(hist1, sel);
    hist2s_k <<<NBLK, 256, 0, stream>>>(Dbuf, sel, h2a, h2b);
    sel2a_k  <<<2048, 256, 0, stream>>>(h2a, h2b, part);
    sel2b_k  <<<1, 1024, 0, stream>>>(part, h2a, h2b, sel, sigp);
    ksum_k   <<<NBLK, 256, 0, stream>>>(Dbuf, sigp, bsums);
  } else {
    pair_k<0><<<NBLK, 256, 0, stream>>>(XY, sq, hist1, h2a, h2b, sel, sigp, bsums, Dbuf);
    sel1_k   <<<1, 256, 0, stream>>>(hist1, sel);
    pair_k<1><<<NBLK, 256, 0, stream>>>(XY, sq, hist1, h2a, h2b, sel, sigp, bsums, Dbuf);
    sel2a_k  <<<2048, 256, 0, stream>>>(h2a, h2b, part);
    sel2b_k  <<<1, 1024, 0, stream>>>(part, h2a, h2b, sel, sigp);
    pair_k<2><<<NBLK, 256, 0, stream>>>(XY, sq, hist1, h2a, h2b, sel, sigp, bsums, Dbuf);
  }

  final_k  <<<1, 256, 0, stream>>>(bsums, out);
}

// Round 7
// 565.306 us; speedup vs baseline: 2.0741x; 1.3021x over previous
//
#include <hip/hip_runtime.h>
#include <math.h>

#define NN    4096      // nodes per graph
#define DF    128       // input feature dim
#define NE    65536     // edges per graph
#define NTOT  8192      // total rows (2 graphs)
#define DP    132       // padded feature dim (130 used + 2 zero)
#define TILE  128
#define KC    44        // K-chunk (3*44 = 132)
#define NTILE 64        // 8192/128
#define NBLK  2080      // 64*65/2 upper-tri tiles
#define R0    16775167u // m/2-1, m = 8192*8191/2 = 33550336
#define R1    16775168u
#define FINF  __int_as_float(0x7f800000)

// ---- workspace layout (bytes) ----
#define OFF_MB   0ULL                // u32[2][4096*128] 4 MB (zeroed)
#define OFF_H1   4194304ULL          // u32[4096]  16 KB (zeroed)
#define OFF_HMID 4210688ULL          // u32[2048]   8 KB (zeroed)
#define OFF_HLOW 4218880ULL          // u32[2048]   8 KB (zeroed)
#define OFF_DEG  4227072ULL          // int[2][4096] 32 KB (zeroed)
#define OFF_TRI  4259840ULL          // int[2][4096] 32 KB (zeroed)
#define ZERO_BYTES 4292608ULL
#define OFF_XY   4292608ULL          // float[8192*132] 4.33 MB
#define OFF_SQ   8617984ULL          // float[8192]
#define OFF_BS   8650752ULL          // double[2080]
#define OFF_SEL  8667392ULL          // u32[16]
#define OFF_SIG  8667456ULL          // float[1] (+pad)
#define OFF_D    8667520ULL          // float[2080*16384] = 136,314,880 B
#define DBYTES   136314880ULL
#define WS_CACHED (OFF_D + DBYTES)   // 144,982,400

// sel[] layout: [0]=b0 [1]=b1 (12-bit buckets)  [2],[3]=in-bucket ranks
//               [4],[5]=10-bit mid segments     [6],[7]=residual ranks

// ---------------- build: M bitset + in-degree ----------------
__global__ __launch_bounds__(256) void build_k(const int* __restrict__ eiS, const int* __restrict__ eiT,
                                               unsigned* __restrict__ Mb, int* __restrict__ degc){
  int gid = blockIdx.x*256 + threadIdx.x;      // 0 .. 2*65536-1
  int g = gid >> 16, e = gid & 65535;
  const int* ei = g ? eiT : eiS;
  unsigned* M = Mb + (size_t)g*NN*128;
  int* dg = degc + g*NN;
  int s = ei[e], t = ei[NE + e];
  atomicOr(&M[(size_t)s*128 + (t>>5)], 1u << (t&31));
  atomicAdd(&dg[t], 1);
}

// ---------------- triangles: tri_cnt[i] = sum_e M[i,s]&M[i,t] ----------------
#define GPB 16
__global__ __launch_bounds__(256) void tri_k(const int* __restrict__ eiS, const int* __restrict__ eiT,
                                             const unsigned* __restrict__ Mb, int* __restrict__ tric){
  int g  = blockIdx.x >> 8;
  int nb = blockIdx.x & 255;
  const int* ei = g ? eiT : eiS;
  const unsigned* M = Mb + (size_t)g*NN*128;
  int* tr = tric + g*NN;
  __shared__ unsigned lm[128*20];   // [word][node], stride 20 keeps uint4 16B-aligned
  __shared__ int lcnt[GPB];
  int tid = threadIdx.x;
  for(int idx=tid; idx<128*GPB; idx+=256){
    int w = idx & 127, gg = idx >> 7;
    lm[w*20+gg] = M[(size_t)(nb*GPB+gg)*128 + w];
  }
  if(tid < GPB) lcnt[tid]=0;
  __syncthreads();
  int cnt[GPB];
  #pragma unroll
  for(int q=0;q<GPB;++q) cnt[q]=0;
  for(int e=tid; e<NE; e+=256){
    int s = ei[e], t = ei[NE+e];
    int ws_ = s>>5, bs = s&31, wt = t>>5, bt = t&31;
    const uint4* ps4 = (const uint4*)&lm[ws_*20];
    const uint4* pt4 = (const uint4*)&lm[wt*20];
    unsigned a_[GPB], b_[GPB];
    ((uint4*)a_)[0]=ps4[0]; ((uint4*)a_)[1]=ps4[1]; ((uint4*)a_)[2]=ps4[2]; ((uint4*)a_)[3]=ps4[3];
    ((uint4*)b_)[0]=pt4[0]; ((uint4*)b_)[1]=pt4[1]; ((uint4*)b_)[2]=pt4[2]; ((uint4*)b_)[3]=pt4[3];
    #pragma unroll
    for(int q=0;q<GPB;++q) cnt[q] += (int)((a_[q]>>bs) & (b_[q]>>bt) & 1u);
  }
  #pragma unroll
  for(int q=0;q<GPB;++q){
    int v = cnt[q];
    for(int off=32; off; off>>=1) v += __shfl_down(v, off);
    if((tid&63)==0) atomicAdd(&lcnt[q], v);
  }
  __syncthreads();
  if(tid < GPB) tr[nb*GPB + tid] = lcnt[tid];
}

// ---------------- finalize: struct features -> XY rows + sq norms ----------------
__global__ __launch_bounds__(64) void finalize_k(const float* __restrict__ featS, const float* __restrict__ featT,
                                                 const unsigned* __restrict__ Mb, const int* __restrict__ degc,
                                                 const int* __restrict__ tric, float* __restrict__ XY,
                                                 float* __restrict__ sq){
  int b = blockIdx.x;              // 0..8191
  int g = b >> 12, i = b & 4095;
  int lane = threadIdx.x;          // 64
  const unsigned* Mr = Mb + (size_t)g*NN*128 + (size_t)i*128;
  int pc = __popc(Mr[lane]) + __popc(Mr[64+lane]);
  for(int off=32; off; off>>=1) pc += __shfl_down(pc, off);
  pc = __shfl(pc, 0);
  const float* feats = g ? featT : featS;
  float* row = XY + (size_t)(g*NN + i)*DP;
  float v0 = feats[(size_t)i*DF + lane];
  float v1 = feats[(size_t)i*DF + 64 + lane];
  row[lane] = v0; row[64+lane] = v1;
  float s0 = v0*v0 + v1*v1;
  if(lane==0){
    float degf = (float)degc[g*NN+i];
    float nd   = degf / 4095.0f;                 // deg/(n-1)
    float dd   = (float)pc;
    float tri  = 0.5f * (float)tric[g*NN+i];
    float me   = dd*(dd-1.0f)*0.5f;
    float cl   = (dd >= 2.0f) ? (tri / fmaxf(me, 1.0f)) : 0.0f;
    float f0 = 0.1f * nd;
    float f1 = 0.1f * log1pf(cl);
    row[128]=f0; row[129]=f1; row[130]=0.0f; row[131]=0.0f;
    s0 += f0*f0 + f1*f1;
  }
  for(int off=32; off; off>>=1) s0 += __shfl_down(s0, off);
  if(lane==0) sq[g*NN+i] = s0;
}

// ---------------- pairwise tile passes ----------------
// MODE 3: hist12 + store distances (cached path)
// MODE 0: hist12 only (fallback)  MODE 4: mid-hist recompute  MODE 5: low-hist recompute
// MODE 2: kernel sums recompute (fallback)
template<int MODE>
__global__ __launch_bounds__(256) void pair_k(const float* __restrict__ XY, const float* __restrict__ sq,
                                              unsigned* __restrict__ hist1, unsigned* __restrict__ hmid,
                                              unsigned* __restrict__ hlow, const unsigned* __restrict__ sel,
                                              const float* __restrict__ sigp, double* __restrict__ blockSums,
                                              float* __restrict__ Dout){
  int t = blockIdx.x, bi = 0;
  while(t >= NTILE - bi){ t -= NTILE - bi; ++bi; }
  int bj = bi + t;                              // bi <= bj, upper-tri tile
  __shared__ float As[KC][TILE];
  __shared__ float Bs[KC][TILE];
  int tid = threadIdx.x;
  int trw = tid >> 4, tcl = tid & 15;
  float acc[8][8];
  #pragma unroll
  for(int r=0;r<8;++r){
    #pragma unroll
    for(int c=0;c<8;++c) acc[r][c]=0.f;
  }
  int i0 = bi*TILE, j0 = bj*TILE;
  for(int kc=0; kc<3; ++kc){
    for(int idx=tid; idx<TILE*11; idx+=256){
      int r = idx/11, q = idx - r*11;
      float4 va = *(const float4*)&XY[(size_t)(i0+r)*DP + kc*KC + q*4];
      float4 vb = *(const float4*)&XY[(size_t)(j0+r)*DP + kc*KC + q*4];
      int k = q*4;
      As[k][r]=va.x; As[k+1][r]=va.y; As[k+2][r]=va.z; As[k+3][r]=va.w;
      Bs[k][r]=vb.x; Bs[k+1][r]=vb.y; Bs[k+2][r]=vb.z; Bs[k+3][r]=vb.w;
    }
    __syncthreads();
    #pragma unroll 4
    for(int k=0;k<KC;++k){
      float a[8], b[8];
      *(float4*)&a[0] = *(const float4*)&As[k][trw*8];
      *(float4*)&a[4] = *(const float4*)&As[k][trw*8+4];
      *(float4*)&b[0] = *(const float4*)&Bs[k][tcl*8];
      *(float4*)&b[4] = *(const float4*)&Bs[k][tcl*8+4];
      #pragma unroll
      for(int r=0;r<8;++r){
        #pragma unroll
        for(int c=0;c<8;++c) acc[r][c] = fmaf(a[r], b[c], acc[r][c]);
      }
    }
    __syncthreads();
  }
  float sqi[8], sqj[8];
  #pragma unroll
  for(int r=0;r<8;++r) sqi[r] = sq[i0 + trw*8 + r];
  #pragma unroll
  for(int c=0;c<8;++c) sqj[c] = sq[j0 + tcl*8 + c];

  if constexpr (MODE==0 || MODE==3){
    __shared__ unsigned lh[4096];
    for(int x=tid;x<4096;x+=256) lh[x]=0u;
    __syncthreads();
    #pragma unroll
    for(int r=0;r<8;++r){
      float rowd[8];
      #pragma unroll
      for(int c=0;c<8;++c){
        int i = i0 + trw*8 + r, j = j0 + tcl*8 + c;
        bool valid = (bi!=bj) || (i<j);
        float d = fmaxf(sqi[r]+sqj[c]-2.0f*acc[r][c], 0.0f);
        rowd[c] = valid ? d : FINF;
        if(valid) atomicAdd(&lh[__float_as_uint(d)>>20], 1u);
      }
      if constexpr (MODE==3){
        float* rp = Dout + (size_t)blockIdx.x*16384 + (size_t)(trw*8+r)*128 + tcl*8;
        *(float4*)rp       = make_float4(rowd[0],rowd[1],rowd[2],rowd[3]);
        *(float4*)(rp+4)   = make_float4(rowd[4],rowd[5],rowd[6],rowd[7]);
      }
    }
    __syncthreads();
    for(int x=tid;x<4096;x+=256){ unsigned v=lh[x]; if(v) atomicAdd(&hist1[x], v); }
  } else if constexpr (MODE==4 || MODE==5){
    __shared__ unsigned lh2[2048];
    for(int x=tid;x<2048;x+=256) lh2[x]=0u;
    __syncthreads();
    unsigned m0, m1;
    if constexpr (MODE==4){ m0=sel[0]; m1=sel[1]; }
    else                  { m0=(sel[0]<<10)|sel[4]; m1=(sel[1]<<10)|sel[5]; }
    #pragma unroll
    for(int r=0;r<8;++r){
      #pragma unroll
      for(int c=0;c<8;++c){
        int i = i0 + trw*8 + r, j = j0 + tcl*8 + c;
        if(bi!=bj || i<j){
          float d = fmaxf(sqi[r]+sqj[c]-2.0f*acc[r][c], 0.0f);
          unsigned bits = __float_as_uint(d);
          unsigned key = (MODE==4) ? (bits>>20) : (bits>>10);
          unsigned bin = (MODE==4) ? ((bits>>10)&1023u) : (bits&1023u);
          if(key==m0)      atomicAdd(&lh2[bin], 1u);
          else if(key==m1) atomicAdd(&lh2[1024+bin], 1u);
        }
      }
    }
    __syncthreads();
    unsigned* hout = (MODE==4) ? hmid : hlow;
    for(int x=tid;x<2048;x+=256){ unsigned v=lh2[x]; if(v) atomicAdd(&hout[x], v); }
  } else {
    float sig = *sigp;
    float inv = 1.0f/sig;
    float k0=2.0f*inv, k1=inv, k2=0.5f*inv, k3=0.25f*inv, k4=0.125f*inv;
    double lsum = 0.0;
    #pragma unroll
    for(int r=0;r<8;++r){
      #pragma unroll
      for(int c=0;c<8;++c){
        int i = i0 + trw*8 + r, j = j0 + tcl*8 + c;
        if(bi!=bj || i<j){
          float d = fmaxf(sqi[r]+sqj[c]-2.0f*acc[r][c], 0.0f);
          float kv = expf(-d*k0)+expf(-d*k1)+expf(-d*k2)+expf(-d*k3)+expf(-d*k4);
          lsum += (double)kv;
        }
      }
    }
    for(int off=32; off; off>>=1) lsum += __shfl_down(lsum, off);
    __shared__ double redbuf[4];
    if((tid&63)==0) redbuf[tid>>6] = lsum;
    __syncthreads();
    if(tid==0) blockSums[blockIdx.x] = (redbuf[0]+redbuf[1]+redbuf[2]+redbuf[3])*0.2; // /KERNEL_NUM
  }
}

// ---------------- streaming hierarchical hist over cached D ----------------
// LVL 0: match top-12, bin = bits[10:20)   LVL 1: match top-22, bin = bits[0:10)
template<int LVL>
__global__ __launch_bounds__(256) void hist_stream_k(const float* __restrict__ D, const unsigned* __restrict__ sel,
                                                     unsigned* __restrict__ hout){
  __shared__ unsigned lh[2048];
  int tid = threadIdx.x;
  for(int x=tid;x<2048;x+=256) lh[x]=0u;
  __syncthreads();
  unsigned m0, m1;
  if constexpr (LVL==0){ m0=sel[0]; m1=sel[1]; }
  else                 { m0=(sel[0]<<10)|sel[4]; m1=(sel[1]<<10)|sel[5]; }
  const float4* P = (const float4*)(D + (size_t)blockIdx.x*16384);
  #pragma unroll
  for(int k=0;k<16;++k){
    float4 v = P[tid + k*256];
    float vals[4] = {v.x, v.y, v.z, v.w};
    #pragma unroll
    for(int q=0;q<4;++q){
      unsigned bits = __float_as_uint(vals[q]);   // +inf sentinel never matches finite key
      unsigned key = (LVL==0) ? (bits>>20) : (bits>>10);
      unsigned bin = (LVL==0) ? ((bits>>10)&1023u) : (bits&1023u);
      if(key==m0)      atomicAdd(&lh[bin], 1u);
      else if(key==m1) atomicAdd(&lh[1024+bin], 1u);
    }
  }
  __syncthreads();
  for(int x=tid;x<2048;x+=256){ unsigned v=lh[x]; if(v) atomicAdd(&hout[x], v); }
}

// ---------------- streaming kernel sums over cached distances ----------------
__global__ __launch_bounds__(256) void ksum_k(const float* __restrict__ D, const float* __restrict__ sigp,
                                              double* __restrict__ blockSums){
  float sig = *sigp;
  float inv = 1.0f/sig;
  float k0=2.0f*inv, k1=inv, k2=0.5f*inv, k3=0.25f*inv, k4=0.125f*inv;
  const float4* P = (const float4*)(D + (size_t)blockIdx.x*16384);
  int tid = threadIdx.x;
  double lsum = 0.0;
  #pragma unroll
  for(int k=0;k<16;++k){
    float4 v = P[tid + k*256];
    float vals[4] = {v.x, v.y, v.z, v.w};
    #pragma unroll
    for(int q=0;q<4;++q){
      float d = vals[q];                   // +inf sentinel -> expf(-inf)=0 contributes nothing
      float kv = expf(-d*k0)+expf(-d*k1)+expf(-d*k2)+expf(-d*k3)+expf(-d*k4);
      lsum += (double)kv;
    }
  }
  for(int off=32; off; off>>=1) lsum += __shfl_down(lsum, off);
  __shared__ double redbuf[4];
  if((tid&63)==0) redbuf[tid>>6] = lsum;
  __syncthreads();
  if(tid==0) blockSums[blockIdx.x] = (redbuf[0]+redbuf[1]+redbuf[2]+redbuf[3])*0.2;
}

// ---------------- selection 1: find 12-bit bucket + in-bucket ranks ----------------
__global__ __launch_bounds__(256) void sel1_k(const unsigned* __restrict__ hist1, unsigned* __restrict__ sel){
  __shared__ unsigned part[256];
  int tid = threadIdx.x;
  unsigned s = 0;
  #pragma unroll
  for(int k=0;k<16;++k) s += hist1[tid*16+k];
  part[tid] = s;
  __syncthreads();
  if(tid==0){
    const unsigned ranks[2] = {R0, R1};
    unsigned segs[2], bases[2];
    unsigned cum = 0; int found = 0;
    for(int i=0; i<256 && found<2; ++i){
      unsigned nx = cum + part[i];
      while(found<2 && ranks[found] < nx){ segs[found]=i; bases[found]=cum; ++found; }
      cum = nx;
    }
    for(int tg=0; tg<2; ++tg){
      unsigned c2 = bases[tg];
      for(int b=segs[tg]*16;; ++b){
        unsigned nx = c2 + hist1[b];
        if(ranks[tg] < nx){ sel[tg]=(unsigned)b; sel[2+tg]=ranks[tg]-c2; break; }
        c2 = nx;
      }
    }
  }
}

// ---------------- selection B: 10-bit mid segment + residual rank ----------------
__global__ __launch_bounds__(1024) void selB_k(const unsigned* __restrict__ hmid, unsigned* __restrict__ sel){
  __shared__ unsigned buf[1024];
  __shared__ unsigned res[4];       // seg0, rem0, seg1, rem1
  int tid = threadIdx.x;
  for(int tgt=0; tgt<2; ++tgt){
    bool useA = (tgt==0) || (sel[1]==sel[0]);
    const unsigned* H = hmid + (useA ? 0 : 1024);
    unsigned rank = sel[2+tgt];
    buf[tid] = H[tid];
    __syncthreads();
    for(int off=1; off<1024; off<<=1){
      unsigned v = buf[tid];
      unsigned a = (tid>=off) ? buf[tid-off] : 0u;
      __syncthreads();
      buf[tid] = v + a;
      __syncthreads();
    }
    unsigned prev = tid ? buf[tid-1] : 0u;
    if(rank < buf[tid] && rank >= prev){ res[2*tgt]=(unsigned)tid; res[2*tgt+1]=rank-prev; }
    __syncthreads();
  }
  if(tid==0){ sel[4]=res[0]; sel[6]=res[1]; sel[5]=res[2]; sel[7]=res[3]; }
}

// ---------------- selection C: low 10 bits -> exact order stats -> sigma ----------------
__global__ __launch_bounds__(1024) void selC_k(const unsigned* __restrict__ hlow, const unsigned* __restrict__ sel,
                                               float* __restrict__ sigp){
  __shared__ unsigned buf[1024];
  __shared__ unsigned outbits[2];
  int tid = threadIdx.x;
  for(int tgt=0; tgt<2; ++tgt){
    bool useA = (tgt==0) || ((sel[1]==sel[0]) && (sel[5]==sel[4]));
    const unsigned* H = hlow + (useA ? 0 : 1024);
    unsigned rank = sel[6+tgt];
    buf[tid] = H[tid];
    __syncthreads();
    for(int off=1; off<1024; off<<=1){
      unsigned v = buf[tid];
      unsigned a = (tid>=off) ? buf[tid-off] : 0u;
      __syncthreads();
      buf[tid] = v + a;
      __syncthreads();
    }
    unsigned prev = tid ? buf[tid-1] : 0u;
    if(rank < buf[tid] && rank >= prev){
      outbits[tgt] = (sel[tgt]<<20) | (sel[4+tgt]<<10) | (unsigned)tid;
    }
    __syncthreads();
  }
  if(tid==0){
    float v0 = __uint_as_float(outbits[0]);
    float v1 = __uint_as_float(outbits[1]);
    *sigp = 0.5f*(v0+v1);
  }
}

// ---------------- final reduction: MMD ----------------
__global__ __launch_bounds__(256) void final_k(const double* __restrict__ blockSums, float* __restrict__ out){
  __shared__ double cls[3][256];
  int tid = threadIdx.x;
  double l0=0, l1=0, l2=0;
  for(int b=tid; b<NBLK; b+=256){
    int t=b, bi=0;
    while(t >= NTILE - bi){ t -= NTILE - bi; ++bi; }
    int bj = bi + t;
    double v = blockSums[b];
    if(bj < 32) l0 += v;          // XX
    else if(bi >= 32) l2 += v;    // YY
    else l1 += v;                 // XY
  }
  cls[0][tid]=l0; cls[1][tid]=l1; cls[2][tid]=l2;
  __syncthreads();
  for(int off=128; off; off>>=1){
    if(tid<off){ cls[0][tid]+=cls[0][tid+off]; cls[1][tid]+=cls[1][tid+off]; cls[2][tid]+=cls[2][tid+off]; }
    __syncthreads();
  }
  if(tid==0){
    double sxx=cls[0][0], sxy=cls[1][0], syy=cls[2][0];
    double mxx = (2.0*sxx)/((double)NN*(NN-1));   // trace cancels: K(0)=1 per row
    double myy = (2.0*syy)/((double)NN*(NN-1));
    double mxy = sxy/((double)NN*(double)NN);
    double r = mxx + myy - 2.0*mxy;
    out[0] = fmaxf((float)r, 0.0f);
  }
}

extern "C" void kernel_launch(void* const* d_in, const int* in_sizes, int n_in,
                              void* d_out, int out_size, void* d_ws, size_t ws_size,
                              hipStream_t stream){
  (void)in_sizes; (void)n_in; (void)out_size;
  const float* featS = (const float*)d_in[0];
  const float* featT = (const float*)d_in[1];
  const int*   eiS   = (const int*)d_in[2];
  const int*   eiT   = (const int*)d_in[3];
  char* ws = (char*)d_ws;
  unsigned* Mb    = (unsigned*)(ws + OFF_MB);
  unsigned* hist1 = (unsigned*)(ws + OFF_H1);
  unsigned* hmid  = (unsigned*)(ws + OFF_HMID);
  unsigned* hlow  = (unsigned*)(ws + OFF_HLOW);
  int*      degc  = (int*)(ws + OFF_DEG);
  int*      tric  = (int*)(ws + OFF_TRI);
  float*    XY    = (float*)(ws + OFF_XY);
  float*    sq    = (float*)(ws + OFF_SQ);
  double*   bsums = (double*)(ws + OFF_BS);
  unsigned* sel   = (unsigned*)(ws + OFF_SEL);
  float*    sigp  = (float*)(ws + OFF_SIG);
  float*    Dbuf  = (float*)(ws + OFF_D);
  float*    out   = (float*)d_out;

  const bool cached = (ws_size >= WS_CACHED);   // launch-constant -> graph-capture safe

  hipMemsetAsync(ws, 0, (size_t)ZERO_BYTES, stream);

  build_k   <<<512, 256, 0, stream>>>(eiS, eiT, Mb, degc);
  tri_k     <<<512, 256, 0, stream>>>(eiS, eiT, Mb, tric);
  finalize_k<<<NTOT, 64, 0, stream>>>(featS, featT, Mb, degc, tric, XY, sq);

  if(cached){
    pair_k<3>       <<<NBLK, 256, 0, stream>>>(XY, sq, hist1, hmid, hlow, sel, sigp, bsums, Dbuf);
    sel1_k          <<<1, 256, 0, stream>>>(hist1, sel);
    hist_stream_k<0><<<NBLK, 256, 0, stream>>>(Dbuf, sel, hmid);
    selB_k          <<<1, 1024, 0, stream>>>(hmid, sel);
    hist_stream_k<1><<<NBLK, 256, 0, stream>>>(Dbuf, sel, hlow);
    selC_k          <<<1, 1024, 0, stream>>>(hlow, sel, sigp);
    ksum_k          <<<NBLK, 256, 0, stream>>>(Dbuf, sigp, bsums);
  } else {
    pair_k<0>       <<<NBLK, 256, 0, stream>>>(XY, sq, hist1, hmid, hlow, sel, sigp, bsums, Dbuf);
    sel1_k          <<<1, 256, 0, stream>>>(hist1, sel);
    pair_k<4>       <<<NBLK, 256, 0, stream>>>(XY, sq, hist1, hmid, hlow, sel, sigp, bsums, Dbuf);
    selB_k          <<<1, 1024, 0, stream>>>(hmid, sel);
    pair_k<5>       <<<NBLK, 256, 0, stream>>>(XY, sq, hist1, hmid, hlow, sel, sigp, bsums, Dbuf);
    selC_k          <<<1, 1024, 0, stream>>>(hlow, sel, sigp);
    pair_k<2>       <<<NBLK, 256, 0, stream>>>(XY, sq, hist1, hmid, hlow, sel, sigp, bsums, Dbuf);
  }

  final_k  <<<1, 256, 0, stream>>>(bsums, out);
}

// Round 9
// 541.113 us; speedup vs baseline: 2.1668x; 1.0447x over previous
//
#include <hip/hip_runtime.h>
#include <math.h>

#define NN    4096      // nodes per graph
#define DF    128       // input feature dim
#define NE    65536     // edges per graph
#define NTOT  8192      // total rows (2 graphs)
#define TILE  128
#define KC    44        // K-chunk (3*44 = 132)
#define NTILE 64        // 8192/128
#define NBLK  2080      // 64*65/2 upper-tri tiles
#define R0    16775167u // m/2-1, m = 8192*8191/2 = 33550336
#define R1    16775168u
#define FINF  __int_as_float(0x7f800000)

// ---- workspace layout (bytes) ----
#define OFF_MB   0ULL                // u32[2][4096*128] 4 MB (zeroed)
#define OFF_H1   4194304ULL          // u32[4096]  16 KB (zeroed)
#define OFF_HMID 4210688ULL          // u32[2048]   8 KB (zeroed)
#define OFF_HLOW 4218880ULL          // u32[2048]   8 KB (zeroed)
#define OFF_DEG  4227072ULL          // int[2][4096] 32 KB (zeroed)
#define OFF_TRI  4259840ULL          // int[2][4096] 32 KB (zeroed)
#define ZERO_BYTES 4292608ULL
#define OFF_XYT  4292608ULL          // float[132][8192] 4.33 MB (k-major transposed)
#define OFF_SQ   8617984ULL          // float[8192]
#define OFF_BS   8650752ULL          // double[2080]
#define OFF_SEL  8667392ULL          // u32[16]
#define OFF_SIG  8667456ULL          // float[1] (+pad)
#define OFF_D    8667520ULL          // float[2080*16384] = 136,314,880 B
#define DBYTES   136314880ULL
#define WS_CACHED (OFF_D + DBYTES)   // 144,982,400

// sel[] layout: [0]=b0 [1]=b1 (12-bit buckets)  [2],[3]=in-bucket ranks
//               [4],[5]=10-bit mid segments     [6],[7]=residual ranks

// ---------------- build: M bitset + in-degree ----------------
__global__ __launch_bounds__(256) void build_k(const int* __restrict__ eiS, const int* __restrict__ eiT,
                                               unsigned* __restrict__ Mb, int* __restrict__ degc){
  int gid = blockIdx.x*256 + threadIdx.x;      // 0 .. 2*65536-1
  int g = gid >> 16, e = gid & 65535;
  const int* ei = g ? eiT : eiS;
  unsigned* M = Mb + (size_t)g*NN*128;
  int* dg = degc + g*NN;
  int s = ei[e], t = ei[NE + e];
  atomicOr(&M[(size_t)s*128 + (t>>5)], 1u << (t&31));
  atomicAdd(&dg[t], 1);
}

// ---------------- triangles: tri_cnt[i] = sum_e M[i,s]&M[i,t] ----------------
#define GPB 16
__global__ __launch_bounds__(256) void tri_k(const int* __restrict__ eiS, const int* __restrict__ eiT,
                                             const unsigned* __restrict__ Mb, int* __restrict__ tric){
  int g  = blockIdx.x >> 8;
  int nb = blockIdx.x & 255;
  const int* ei = g ? eiT : eiS;
  const unsigned* M = Mb + (size_t)g*NN*128;
  int* tr = tric + g*NN;
  __shared__ unsigned lm[128*20];   // [word][node], stride 20 keeps uint4 16B-aligned
  __shared__ int lcnt[GPB];
  int tid = threadIdx.x;
  for(int idx=tid; idx<128*GPB; idx+=256){
    int w = idx & 127, gg = idx >> 7;
    lm[w*20+gg] = M[(size_t)(nb*GPB+gg)*128 + w];
  }
  if(tid < GPB) lcnt[tid]=0;
  __syncthreads();
  int cnt[GPB];
  #pragma unroll
  for(int q=0;q<GPB;++q) cnt[q]=0;
  for(int e=tid; e<NE; e+=256){
    int s = ei[e], t = ei[NE+e];
    int ws_ = s>>5, bs = s&31, wt = t>>5, bt = t&31;
    const uint4* ps4 = (const uint4*)&lm[ws_*20];
    const uint4* pt4 = (const uint4*)&lm[wt*20];
    unsigned a_[GPB], b_[GPB];
    ((uint4*)a_)[0]=ps4[0]; ((uint4*)a_)[1]=ps4[1]; ((uint4*)a_)[2]=ps4[2]; ((uint4*)a_)[3]=ps4[3];
    ((uint4*)b_)[0]=pt4[0]; ((uint4*)b_)[1]=pt4[1]; ((uint4*)b_)[2]=pt4[2]; ((uint4*)b_)[3]=pt4[3];
    #pragma unroll
    for(int q=0;q<GPB;++q) cnt[q] += (int)((a_[q]>>bs) & (b_[q]>>bt) & 1u);
  }
  #pragma unroll
  for(int q=0;q<GPB;++q){
    int v = cnt[q];
    for(int off=32; off; off>>=1) v += __shfl_down(v, off);
    if((tid&63)==0) atomicAdd(&lcnt[q], v);
  }
  __syncthreads();
  if(tid < GPB) tr[nb*GPB + tid] = lcnt[tid];
}

// ---------------- finalize: struct features -> XYT columns + sq norms ----------------
__global__ __launch_bounds__(64) void finalize_k(const float* __restrict__ featS, const float* __restrict__ featT,
                                                 const unsigned* __restrict__ Mb, const int* __restrict__ degc,
                                                 const int* __restrict__ tric, float* __restrict__ XYT,
                                                 float* __restrict__ sq){
  int b = blockIdx.x;              // 0..8191
  int g = b >> 12, i = b & 4095;
  int lane = threadIdx.x;          // 64
  const unsigned* Mr = Mb + (size_t)g*NN*128 + (size_t)i*128;
  int pc = __popc(Mr[lane]) + __popc(Mr[64+lane]);
  for(int off=32; off; off>>=1) pc += __shfl_down(pc, off);
  pc = __shfl(pc, 0);
  const float* feats = g ? featT : featS;
  int n = g*NN + i;                // column in XYT
  float v0 = feats[(size_t)i*DF + lane];
  float v1 = feats[(size_t)i*DF + 64 + lane];
  XYT[(size_t)lane*NTOT + n]      = v0;
  XYT[(size_t)(64+lane)*NTOT + n] = v1;
  float s0 = v0*v0 + v1*v1;
  if(lane==0){
    float degf = (float)degc[g*NN+i];
    float nd   = degf / 4095.0f;                 // deg/(n-1)
    float dd   = (float)pc;
    float tri  = 0.5f * (float)tric[g*NN+i];
    float me   = dd*(dd-1.0f)*0.5f;
    float cl   = (dd >= 2.0f) ? (tri / fmaxf(me, 1.0f)) : 0.0f;
    float f0 = 0.1f * nd;
    float f1 = 0.1f * log1pf(cl);
    XYT[(size_t)128*NTOT + n] = f0;
    XYT[(size_t)129*NTOT + n] = f1;
    XYT[(size_t)130*NTOT + n] = 0.0f;
    XYT[(size_t)131*NTOT + n] = 0.0f;
    s0 += f0*f0 + f1*f1;
  }
  for(int off=32; off; off>>=1) s0 += __shfl_down(s0, off);
  if(lane==0) sq[g*NN+i] = s0;
}

// ---------------- pairwise tile passes ----------------
// MODE 3: hist12 + store distances (cached path)
// MODE 0: hist12 only (fallback)  MODE 4: mid-hist recompute  MODE 5: low-hist recompute
// MODE 2: kernel sums recompute (fallback)
template<int MODE>
__global__ __launch_bounds__(256) void pair_k(const float* __restrict__ XYT, const float* __restrict__ sq,
                                              unsigned* __restrict__ hist1, unsigned* __restrict__ hmid,
                                              unsigned* __restrict__ hlow, const unsigned* __restrict__ sel,
                                              const float* __restrict__ sigp, double* __restrict__ blockSums,
                                              float* __restrict__ Dout){
  int t = blockIdx.x, bi = 0;
  while(t >= NTILE - bi){ t -= NTILE - bi; ++bi; }
  int bj = bi + t;                              // bi <= bj, upper-tri tile
  // 45056 B: As[44][128] | Bs[44][128]; aliased as histogram buffers in the epilogue
  __shared__ float4 smem4[2816];
  float* As = (float*)smem4;
  float* Bs = As + KC*TILE;
  int tid = threadIdx.x;
  int trw = tid >> 4, tcl = tid & 15;
  float acc[8][8];
  #pragma unroll
  for(int r=0;r<8;++r){
    #pragma unroll
    for(int c=0;c<8;++c) acc[r][c]=0.f;
  }
  int i0 = bi*TILE, j0 = bj*TILE;
  for(int kc=0; kc<3; ++kc){
    // stage from k-major XYT: float4 global load -> b128 LDS write, lane-linear (conflict-free)
    #pragma unroll
    for(int s=0;s<11;++s){
      int idx = tid + s*256;                 // 0..2815
      int isB = idx >= 1408;
      int l = isB ? (idx-1408) : idx;
      int k = l >> 5, c4 = l & 31;
      int col = (isB ? j0 : i0) + c4*4;
      smem4[idx] = *(const float4*)&XYT[(size_t)(kc*KC+k)*NTOT + col];
    }
    __syncthreads();
    #pragma unroll 4
    for(int k=0;k<KC;++k){
      float a[8], b[8];
      const float* Ak = As + k*TILE;
      const float* Bk = Bs + k*TILE;
      *(float4*)&a[0] = *(const float4*)&Ak[trw*8];
      *(float4*)&a[4] = *(const float4*)&Ak[trw*8+4];
      *(float4*)&b[0] = *(const float4*)&Bk[tcl*8];
      *(float4*)&b[4] = *(const float4*)&Bk[tcl*8+4];
      #pragma unroll
      for(int r=0;r<8;++r){
        #pragma unroll
        for(int c=0;c<8;++c) acc[r][c] = fmaf(a[r], b[c], acc[r][c]);
      }
    }
    __syncthreads();
  }
  float sqi[8], sqj[8];
  #pragma unroll
  for(int r=0;r<8;++r) sqi[r] = sq[i0 + trw*8 + r];
  #pragma unroll
  for(int c=0;c<8;++c) sqj[c] = sq[j0 + tcl*8 + c];

  if constexpr (MODE==0 || MODE==3){
    unsigned* lh = (unsigned*)smem4;        // alias dead tile buffer
    for(int x=tid;x<4096;x+=256) lh[x]=0u;
    __syncthreads();
    #pragma unroll
    for(int r=0;r<8;++r){
      float rowd[8];
      #pragma unroll
      for(int c=0;c<8;++c){
        int i = i0 + trw*8 + r, j = j0 + tcl*8 + c;
        bool valid = (bi!=bj) || (i<j);
        float d = fmaxf(sqi[r]+sqj[c]-2.0f*acc[r][c], 0.0f);
        rowd[c] = valid ? d : FINF;
        if(valid) atomicAdd(&lh[__float_as_uint(d)>>20], 1u);
      }
      if constexpr (MODE==3){
        float* rp = Dout + (size_t)blockIdx.x*16384 + (size_t)(trw*8+r)*128 + tcl*8;
        *(float4*)rp       = make_float4(rowd[0],rowd[1],rowd[2],rowd[3]);
        *(float4*)(rp+4)   = make_float4(rowd[4],rowd[5],rowd[6],rowd[7]);
      }
    }
    __syncthreads();
    for(int x=tid;x<4096;x+=256){ unsigned v=lh[x]; if(v) atomicAdd(&hist1[x], v); }
  } else if constexpr (MODE==4 || MODE==5){
    unsigned* lh2 = (unsigned*)smem4;       // alias dead tile buffer
    for(int x=tid;x<2048;x+=256) lh2[x]=0u;
    __syncthreads();
    unsigned m0, m1;
    if constexpr (MODE==4){ m0=sel[0]; m1=sel[1]; }
    else                  { m0=(sel[0]<<10)|sel[4]; m1=(sel[1]<<10)|sel[5]; }
    #pragma unroll
    for(int r=0;r<8;++r){
      #pragma unroll
      for(int c=0;c<8;++c){
        int i = i0 + trw*8 + r, j = j0 + tcl*8 + c;
        if(bi!=bj || i<j){
          float d = fmaxf(sqi[r]+sqj[c]-2.0f*acc[r][c], 0.0f);
          unsigned bits = __float_as_uint(d);
          unsigned key = (MODE==4) ? (bits>>20) : (bits>>10);
          unsigned bin = (MODE==4) ? ((bits>>10)&1023u) : (bits&1023u);
          if(key==m0)      atomicAdd(&lh2[bin], 1u);
          else if(key==m1) atomicAdd(&lh2[1024+bin], 1u);
        }
      }
    }
    __syncthreads();
    unsigned* hout = (MODE==4) ? hmid : hlow;
    for(int x=tid;x<2048;x+=256){ unsigned v=lh2[x]; if(v) atomicAdd(&hout[x], v); }
  } else {
    float sig = *sigp;
    float inv = 1.0f/sig;
    float k0=2.0f*inv, k1=inv, k2=0.5f*inv, k3=0.25f*inv, k4=0.125f*inv;
    double lsum = 0.0;
    #pragma unroll
    for(int r=0;r<8;++r){
      #pragma unroll
      for(int c=0;c<8;++c){
        int i = i0 + trw*8 + r, j = j0 + tcl*8 + c;
        if(bi!=bj || i<j){
          float d = fmaxf(sqi[r]+sqj[c]-2.0f*acc[r][c], 0.0f);
          float kv = expf(-d*k0)+expf(-d*k1)+expf(-d*k2)+expf(-d*k3)+expf(-d*k4);
          lsum += (double)kv;
        }
      }
    }
    for(int off=32; off; off>>=1) lsum += __shfl_down(lsum, off);
    double* redbuf = (double*)smem4;        // alias dead tile buffer
    if((tid&63)==0) redbuf[tid>>6] = lsum;
    __syncthreads();
    if(tid==0) blockSums[blockIdx.x] = (redbuf[0]+redbuf[1]+redbuf[2]+redbuf[3])*0.2; // /KERNEL_NUM
  }
}

// ---------------- streaming hierarchical hist over cached D ----------------
// LVL 0: match top-12, bin = bits[10:20)   LVL 1: match top-22, bin = bits[0:10)
template<int LVL>
__global__ __launch_bounds__(256) void hist_stream_k(const float* __restrict__ D, const unsigned* __restrict__ sel,
                                                     unsigned* __restrict__ hout){
  __shared__ unsigned lh[2048];
  int tid = threadIdx.x;
  for(int x=tid;x<2048;x+=256) lh[x]=0u;
  __syncthreads();
  unsigned m0, m1;
  if constexpr (LVL==0){ m0=sel[0]; m1=sel[1]; }
  else                 { m0=(sel[0]<<10)|sel[4]; m1=(sel[1]<<10)|sel[5]; }
  const float4* P = (const float4*)(D + (size_t)blockIdx.x*16384);
  #pragma unroll
  for(int k=0;k<16;++k){
    float4 v = P[tid + k*256];
    float vals[4] = {v.x, v.y, v.z, v.w};
    #pragma unroll
    for(int q=0;q<4;++q){
      unsigned bits = __float_as_uint(vals[q]);   // +inf sentinel never matches finite key
      unsigned key = (LVL==0) ? (bits>>20) : (bits>>10);
      unsigned bin = (LVL==0) ? ((bits>>10)&1023u) : (bits&1023u);
      if(key==m0)      atomicAdd(&lh[bin], 1u);
      else if(key==m1) atomicAdd(&lh[1024+bin], 1u);
    }
  }
  __syncthreads();
  for(int x=tid;x<2048;x+=256){ unsigned v=lh[x]; if(v) atomicAdd(&hout[x], v); }
}

// ---------------- streaming kernel sums over cached distances ----------------
__global__ __launch_bounds__(256) void ksum_k(const float* __restrict__ D, const float* __restrict__ sigp,
                                              double* __restrict__ blockSums){
  float sig = *sigp;
  float inv = 1.0f/sig;
  float k0=2.0f*inv, k1=inv, k2=0.5f*inv, k3=0.25f*inv, k4=0.125f*inv;
  const float4* P = (const float4*)(D + (size_t)blockIdx.x*16384);
  int tid = threadIdx.x;
  double lsum = 0.0;
  #pragma unroll
  for(int k=0;k<16;++k){
    float4 v = P[tid + k*256];
    float vals[4] = {v.x, v.y, v.z, v.w};
    #pragma unroll
    for(int q=0;q<4;++q){
      float d = vals[q];                   // +inf sentinel -> expf(-inf)=0 contributes nothing
      float kv = expf(-d*k0)+expf(-d*k1)+expf(-d*k2)+expf(-d*k3)+expf(-d*k4);
      lsum += (double)kv;
    }
  }
  for(int off=32; off; off>>=1) lsum += __shfl_down(lsum, off);
  __shared__ double redbuf[4];
  if((tid&63)==0) redbuf[tid>>6] = lsum;
  __syncthreads();
  if(tid==0) blockSums[blockIdx.x] = (redbuf[0]+redbuf[1]+redbuf[2]+redbuf[3])*0.2;
}

// ---------------- selection 1: find 12-bit bucket + in-bucket ranks ----------------
__global__ __launch_bounds__(256) void sel1_k(const unsigned* __restrict__ hist1, unsigned* __restrict__ sel){
  __shared__ unsigned part[256];
  int tid = threadIdx.x;
  unsigned s = 0;
  #pragma unroll
  for(int k=0;k<16;++k) s += hist1[tid*16+k];
  part[tid] = s;
  __syncthreads();
  if(tid==0){
    const unsigned ranks[2] = {R0, R1};
    unsigned segs[2], bases[2];
    unsigned cum = 0; int found = 0;
    for(int i=0; i<256 && found<2; ++i){
      unsigned nx = cum + part[i];
      while(found<2 && ranks[found] < nx){ segs[found]=i; bases[found]=cum; ++found; }
      cum = nx;
    }
    for(int tg=0; tg<2; ++tg){
      unsigned c2 = bases[tg];
      for(int b=segs[tg]*16;; ++b){
        unsigned nx = c2 + hist1[b];
        if(ranks[tg] < nx){ sel[tg]=(unsigned)b; sel[2+tg]=ranks[tg]-c2; break; }
        c2 = nx;
      }
    }
  }
}

// ---------------- selection B: 10-bit mid segment + residual rank ----------------
__global__ __launch_bounds__(1024) void selB_k(const unsigned* __restrict__ hmid, unsigned* __restrict__ sel){
  __shared__ unsigned buf[1024];
  __shared__ unsigned res[4];       // seg0, rem0, seg1, rem1
  int tid = threadIdx.x;
  for(int tgt=0; tgt<2; ++tgt){
    bool useA = (tgt==0) || (sel[1]==sel[0]);
    const unsigned* H = hmid + (useA ? 0 : 1024);
    unsigned rank = sel[2+tgt];
    buf[tid] = H[tid];
    __syncthreads();
    for(int off=1; off<1024; off<<=1){
      unsigned v = buf[tid];
      unsigned a = (tid>=off) ? buf[tid-off] : 0u;
      __syncthreads();
      buf[tid] = v + a;
      __syncthreads();
    }
    unsigned prev = tid ? buf[tid-1] : 0u;
    if(rank < buf[tid] && rank >= prev){ res[2*tgt]=(unsigned)tid; res[2*tgt+1]=rank-prev; }
    __syncthreads();
  }
  if(tid==0){ sel[4]=res[0]; sel[6]=res[1]; sel[5]=res[2]; sel[7]=res[3]; }
}

// ---------------- selection C: low 10 bits -> exact order stats -> sigma ----------------
__global__ __launch_bounds__(1024) void selC_k(const unsigned* __restrict__ hlow, const unsigned* __restrict__ sel,
                                               float* __restrict__ sigp){
  __shared__ unsigned buf[1024];
  __shared__ unsigned outbits[2];
  int tid = threadIdx.x;
  for(int tgt=0; tgt<2; ++tgt){
    bool useA = (tgt==0) || ((sel[1]==sel[0]) && (sel[5]==sel[4]));
    const unsigned* H = hlow + (useA ? 0 : 1024);
    unsigned rank = sel[6+tgt];
    buf[tid] = H[tid];
    __syncthreads();
    for(int off=1; off<1024; off<<=1){
      unsigned v = buf[tid];
      unsigned a = (tid>=off) ? buf[tid-off] : 0u;
      __syncthreads();
      buf[tid] = v + a;
      __syncthreads();
    }
    unsigned prev = tid ? buf[tid-1] : 0u;
    if(rank < buf[tid] && rank >= prev){
      outbits[tgt] = (sel[tgt]<<20) | (sel[4+tgt]<<10) | (unsigned)tid;
    }
    __syncthreads();
  }
  if(tid==0){
    float v0 = __uint_as_float(outbits[0]);
    float v1 = __uint_as_float(outbits[1]);
    *sigp = 0.5f*(v0+v1);
  }
}

// ---------------- final reduction: MMD ----------------
__global__ __launch_bounds__(256) void final_k(const double* __restrict__ blockSums, float* __restrict__ out){
  __shared__ double cls[3][256];
  int tid = threadIdx.x;
  double l0=0, l1=0, l2=0;
  for(int b=tid; b<NBLK; b+=256){
    int t=b, bi=0;
    while(t >= NTILE - bi){ t -= NTILE - bi; ++bi; }
    int bj = bi + t;
    double v = blockSums[b];
    if(bj < 32) l0 += v;          // XX
    else if(bi >= 32) l2 += v;    // YY
    else l1 += v;                 // XY
  }
  cls[0][tid]=l0; cls[1][tid]=l1; cls[2][tid]=l2;
  __syncthreads();
  for(int off=128; off; off>>=1){
    if(tid<off){ cls[0][tid]+=cls[0][tid+off]; cls[1][tid]+=cls[1][tid+off]; cls[2][tid]+=cls[2][tid+off]; }
    __syncthreads();
  }
  if(tid==0){
    double sxx=cls[0][0], sxy=cls[1][0], syy=cls[2][0];
    double mxx = (2.0*sxx)/((double)NN*(NN-1));   // trace cancels: K(0)=1 per row
    double myy = (2.0*syy)/((double)NN*(NN-1));
    double mxy = sxy/((double)NN*(double)NN);
    double r = mxx + myy - 2.0*mxy;
    out[0] = fmaxf((float)r, 0.0f);
  }
}

extern "C" void kernel_launch(void* const* d_in, const int* in_sizes, int n_in,
                              void* d_out, int out_size, void* d_ws, size_t ws_size,
                              hipStream_t stream){
  (void)in_sizes; (void)n_in; (void)out_size;
  const float* featS = (const float*)d_in[0];
  const float* featT = (const float*)d_in[1];
  const int*   eiS   = (const int*)d_in[2];
  const int*   eiT   = (const int*)d_in[3];
  char* ws = (char*)d_ws;
  unsigned* Mb    = (unsigned*)(ws + OFF_MB);
  unsigned* hist1 = (unsigned*)(ws + OFF_H1);
  unsigned* hmid  = (unsigned*)(ws + OFF_HMID);
  unsigned* hlow  = (unsigned*)(ws + OFF_HLOW);
  int*      degc  = (int*)(ws + OFF_DEG);
  int*      tric  = (int*)(ws + OFF_TRI);
  float*    XYT   = (float*)(ws + OFF_XYT);
  float*    sq    = (float*)(ws + OFF_SQ);
  double*   bsums = (double*)(ws + OFF_BS);
  unsigned* sel   = (unsigned*)(ws + OFF_SEL);
  float*    sigp  = (float*)(ws + OFF_SIG);
  float*    Dbuf  = (float*)(ws + OFF_D);
  float*    out   = (float*)d_out;

  const bool cached = (ws_size >= WS_CACHED);   // launch-constant -> graph-capture safe

  hipMemsetAsync(ws, 0, (size_t)ZERO_BYTES, stream);

  build_k   <<<512, 256, 0, stream>>>(eiS, eiT, Mb, degc);
  tri_k     <<<512, 256, 0, stream>>>(eiS, eiT, Mb, tric);
  finalize_k<<<NTOT, 64, 0, stream>>>(featS, featT, Mb, degc, tric, XYT, sq);

  if(cached){
    pair_k<3>       <<<NBLK, 256, 0, stream>>>(XYT, sq, hist1, hmid, hlow, sel, sigp, bsums, Dbuf);
    sel1_k          <<<1, 256, 0, stream>>>(hist1, sel);
    hist_stream_k<0><<<NBLK, 256, 0, stream>>>(Dbuf, sel, hmid);
    selB_k          <<<1, 1024, 0, stream>>>(hmid, sel);
    hist_stream_k<1><<<NBLK, 256, 0, stream>>>(Dbuf, sel, hlow);
    selC_k          <<<1, 1024, 0, stream>>>(hlow, sel, sigp);
    ksum_k          <<<NBLK, 256, 0, stream>>>(Dbuf, sigp, bsums);
  } else {
    pair_k<0>       <<<NBLK, 256, 0, stream>>>(XYT, sq, hist1, hmid, hlow, sel, sigp, bsums, Dbuf);
    sel1_k          <<<1, 256, 0, stream>>>(hist1, sel);
    pair_k<4>       <<<NBLK, 256, 0, stream>>>(XYT, sq, hist1, hmid, hlow, sel, sigp, bsums, Dbuf);
    selB_k          <<<1, 1024, 0, stream>>>(hmid, sel);
    pair_k<5>       <<<NBLK, 256, 0, stream>>>(XYT, sq, hist1, hmid, hlow, sel, sigp, bsums, Dbuf);
    selC_k          <<<1, 1024, 0, stream>>>(hlow, sel, sigp);
    pair_k<2>       <<<NBLK, 256, 0, stream>>>(XYT, sq, hist1, hmid, hlow, sel, sigp, bsums, Dbuf);
  }

  final_k  <<<1, 256, 0, stream>>>(bsums, out);
}

// Round 10
// 481.805 us; speedup vs baseline: 2.4336x; 1.1231x over previous
//
#include <hip/hip_runtime.h>
#include <math.h>

#define NN    4096      // nodes per graph
#define DF    128       // input feature dim
#define NE    65536     // edges per graph
#define NTOT  8192      // total rows (2 graphs)
#define TILE  128
#define KC    44        // K-chunk (3*44 = 132)
#define NTILE 64        // 8192/128
#define NBLK  2080      // 64*65/2 upper-tri tiles
#define R0    16775167u // m/2-1, m = 8192*8191/2 = 33550336
#define R1    16775168u
#define FINF  __int_as_float(0x7f800000)

// ---- workspace layout (bytes) ----
#define OFF_MB   0ULL                // u32[2][4096*128] 4 MB (zeroed)
#define OFF_H1   4194304ULL          // u32[4096]  16 KB (zeroed)
#define OFF_HMID 4210688ULL          // u32[2048]   8 KB (zeroed)
#define OFF_HLOW 4218880ULL          // u32[2048]   8 KB (zeroed)
#define OFF_DEG  4227072ULL          // int[2][4096] 32 KB (zeroed)
#define OFF_TRI  4259840ULL          // int[2][4096] 32 KB (zeroed)
#define ZERO_BYTES 4292608ULL
#define OFF_XYT  4292608ULL          // float[132][8192] 4.33 MB (k-major transposed)
#define OFF_SQ   8617984ULL          // float[8192]
#define OFF_BS   8650752ULL          // double[2080]
#define OFF_SEL  8667392ULL          // u32[16]
#define OFF_SIG  8667456ULL          // float[1] (+pad)
#define OFF_D    8667520ULL          // float[2080*16384] = 136,314,880 B
#define DBYTES   136314880ULL
#define WS_CACHED (OFF_D + DBYTES)   // 144,982,400

// sel[] layout: [0]=b0 [1]=b1 (12-bit buckets)  [2],[3]=in-bucket ranks
//               [4],[5]=10-bit mid segments     [6],[7]=residual ranks

// ---------------- build: M bitset + in-degree ----------------
__global__ __launch_bounds__(256) void build_k(const int* __restrict__ eiS, const int* __restrict__ eiT,
                                               unsigned* __restrict__ Mb, int* __restrict__ degc){
  int gid = blockIdx.x*256 + threadIdx.x;      // 0 .. 2*65536-1
  int g = gid >> 16, e = gid & 65535;
  const int* ei = g ? eiT : eiS;
  unsigned* M = Mb + (size_t)g*NN*128;
  int* dg = degc + g*NN;
  int s = ei[e], t = ei[NE + e];
  atomicOr(&M[(size_t)s*128 + (t>>5)], 1u << (t&31));
  atomicAdd(&dg[t], 1);
}

// ---------------- triangles v2: bit-transposed mask, VALU-bound ----------------
// tri_cnt[i] = sum_e M[i,s_e] & M[i,t_e].  Block owns 32 nodes; mask[j] bit q =
// M[nb*32+q, j].  Per edge: 2 scalar LDS reads + 32 bit-extract adds.
#define GPB2 32
__global__ __launch_bounds__(512) void tri_k(const int* __restrict__ eiS, const int* __restrict__ eiT,
                                             const unsigned* __restrict__ Mb, int* __restrict__ tric){
  int g  = blockIdx.x >> 7;        // 256 blocks: 128 per graph
  int nb = blockIdx.x & 127;
  const int* ei = g ? eiT : eiS;
  const unsigned* M = Mb + (size_t)g*NN*128;
  __shared__ unsigned rows[GPB2*128];   // 16 KB staged node-rows
  __shared__ unsigned mask[NN];         // 16 KB bit-transposed adjacency
  __shared__ int lcnt[GPB2];
  int tid = threadIdx.x;
  for(int idx=tid; idx<GPB2*128; idx+=512){
    int q = idx >> 7, w = idx & 127;
    rows[q*128 + w] = M[(size_t)(nb*GPB2+q)*128 + w];
  }
  if(tid < GPB2) lcnt[tid] = 0;
  __syncthreads();
  for(int j=tid; j<NN; j+=512){
    int w = j >> 5, b = j & 31;
    unsigned m = 0;
    #pragma unroll
    for(int q=0;q<GPB2;++q) m |= ((rows[q*128+w] >> b) & 1u) << q;
    mask[j] = m;
  }
  __syncthreads();
  int cnt[GPB2];
  #pragma unroll
  for(int q=0;q<GPB2;++q) cnt[q]=0;
  for(int e=tid; e<NE; e+=512){
    int s = ei[e], t = ei[NE+e];
    unsigned both = mask[s] & mask[t];
    #pragma unroll
    for(int q=0;q<GPB2;++q) cnt[q] += (int)((both>>q)&1u);
  }
  #pragma unroll
  for(int q=0;q<GPB2;++q){
    int v = cnt[q];
    for(int off=32; off; off>>=1) v += __shfl_down(v, off);
    if((tid&63)==0) atomicAdd(&lcnt[q], v);
  }
  __syncthreads();
  if(tid < GPB2) tric[g*NN + nb*GPB2 + tid] = lcnt[tid];
}

// ---------------- finalize: struct features -> XYT columns + sq norms ----------------
__global__ __launch_bounds__(64) void finalize_k(const float* __restrict__ featS, const float* __restrict__ featT,
                                                 const unsigned* __restrict__ Mb, const int* __restrict__ degc,
                                                 const int* __restrict__ tric, float* __restrict__ XYT,
                                                 float* __restrict__ sq){
  int b = blockIdx.x;              // 0..8191
  int g = b >> 12, i = b & 4095;
  int lane = threadIdx.x;          // 64
  const unsigned* Mr = Mb + (size_t)g*NN*128 + (size_t)i*128;
  int pc = __popc(Mr[lane]) + __popc(Mr[64+lane]);
  for(int off=32; off; off>>=1) pc += __shfl_down(pc, off);
  pc = __shfl(pc, 0);
  const float* feats = g ? featT : featS;
  int n = g*NN + i;                // column in XYT
  float v0 = feats[(size_t)i*DF + lane];
  float v1 = feats[(size_t)i*DF + 64 + lane];
  XYT[(size_t)lane*NTOT + n]      = v0;
  XYT[(size_t)(64+lane)*NTOT + n] = v1;
  float s0 = v0*v0 + v1*v1;
  if(lane==0){
    float degf = (float)degc[g*NN+i];
    float nd   = degf / 4095.0f;                 // deg/(n-1)
    float dd   = (float)pc;
    float tri  = 0.5f * (float)tric[g*NN+i];
    float me   = dd*(dd-1.0f)*0.5f;
    float cl   = (dd >= 2.0f) ? (tri / fmaxf(me, 1.0f)) : 0.0f;
    float f0 = 0.1f * nd;
    float f1 = 0.1f * log1pf(cl);
    XYT[(size_t)128*NTOT + n] = f0;
    XYT[(size_t)129*NTOT + n] = f1;
    XYT[(size_t)130*NTOT + n] = 0.0f;
    XYT[(size_t)131*NTOT + n] = 0.0f;
    s0 += f0*f0 + f1*f1;
  }
  for(int off=32; off; off>>=1) s0 += __shfl_down(s0, off);
  if(lane==0) sq[g*NN+i] = s0;
}

// ---------------- pairwise tile passes ----------------
// Thread (trw,tcl) owns rows trw*8..+7 and cols {tcl*4..+3} u {64+tcl*4..+3}
// (contiguous float4 groups -> conflict-free LDS reads + coalesced D stores).
// MODE 3: hist12 + store distances (cached path)
// MODE 0: hist12 only (fallback)  MODE 4: mid-hist recompute  MODE 5: low-hist recompute
// MODE 2: kernel sums recompute (fallback)
template<int MODE>
__global__ __launch_bounds__(256) void pair_k(const float* __restrict__ XYT, const float* __restrict__ sq,
                                              unsigned* __restrict__ hist1, unsigned* __restrict__ hmid,
                                              unsigned* __restrict__ hlow, const unsigned* __restrict__ sel,
                                              const float* __restrict__ sigp, double* __restrict__ blockSums,
                                              float* __restrict__ Dout){
  int t = blockIdx.x, bi = 0;
  while(t >= NTILE - bi){ t -= NTILE - bi; ++bi; }
  int bj = bi + t;                              // bi <= bj, upper-tri tile
  // 45056 B: As[44][128] | Bs[44][128]; aliased as histogram buffers in the epilogue
  __shared__ float4 smem4[2816];
  float* As = (float*)smem4;
  float* Bs = As + KC*TILE;
  int tid = threadIdx.x;
  int trw = tid >> 4, tcl = tid & 15;
  float acc[8][8];
  #pragma unroll
  for(int r=0;r<8;++r){
    #pragma unroll
    for(int c=0;c<8;++c) acc[r][c]=0.f;
  }
  int i0 = bi*TILE, j0 = bj*TILE;
  for(int kc=0; kc<3; ++kc){
    // stage from k-major XYT: float4 global load -> b128 LDS write, lane-linear (conflict-free)
    #pragma unroll
    for(int s=0;s<11;++s){
      int idx = tid + s*256;                 // 0..2815
      int isB = idx >= 1408;
      int l = isB ? (idx-1408) : idx;
      int k = l >> 5, c4 = l & 31;
      int col = (isB ? j0 : i0) + c4*4;
      smem4[idx] = *(const float4*)&XYT[(size_t)(kc*KC+k)*NTOT + col];
    }
    __syncthreads();
    #pragma unroll 4
    for(int k=0;k<KC;++k){
      float a[8], b[8];
      const float* Ak = As + k*TILE;
      const float* Bk = Bs + k*TILE;
      *(float4*)&a[0] = *(const float4*)&Ak[trw*8];
      *(float4*)&a[4] = *(const float4*)&Ak[trw*8+4];
      *(float4*)&b[0] = *(const float4*)&Bk[tcl*4];        // contiguous 256B per quarter-wave
      *(float4*)&b[4] = *(const float4*)&Bk[64 + tcl*4];
      #pragma unroll
      for(int r=0;r<8;++r){
        #pragma unroll
        for(int c=0;c<8;++c) acc[r][c] = fmaf(a[r], b[c], acc[r][c]);
      }
    }
    __syncthreads();
  }
  float sqi[8], sqj[8];
  #pragma unroll
  for(int r=0;r<8;++r) sqi[r] = sq[i0 + trw*8 + r];
  #pragma unroll
  for(int c=0;c<8;++c){
    int col = (c<4) ? (tcl*4 + c) : (64 + tcl*4 + (c-4));
    sqj[c] = sq[j0 + col];
  }

  if constexpr (MODE==0 || MODE==3){
    unsigned* lh = (unsigned*)smem4;        // alias dead tile buffer
    for(int x=tid;x<4096;x+=256) lh[x]=0u;
    __syncthreads();
    #pragma unroll
    for(int r=0;r<8;++r){
      float rowd[8];
      #pragma unroll
      for(int c=0;c<8;++c){
        int col = (c<4) ? (tcl*4 + c) : (64 + tcl*4 + (c-4));
        int i = i0 + trw*8 + r, j = j0 + col;
        bool valid = (bi!=bj) || (i<j);
        float d = fmaxf(sqi[r]+sqj[c]-2.0f*acc[r][c], 0.0f);
        rowd[c] = valid ? d : FINF;
        if(valid) atomicAdd(&lh[__float_as_uint(d)>>20], 1u);
      }
      if constexpr (MODE==3){
        float* rp = Dout + (size_t)blockIdx.x*16384 + (size_t)(trw*8+r)*128;
        *(float4*)(rp + tcl*4)      = make_float4(rowd[0],rowd[1],rowd[2],rowd[3]);
        *(float4*)(rp + 64 + tcl*4) = make_float4(rowd[4],rowd[5],rowd[6],rowd[7]);
      }
    }
    __syncthreads();
    for(int x=tid;x<4096;x+=256){ unsigned v=lh[x]; if(v) atomicAdd(&hist1[x], v); }
  } else if constexpr (MODE==4 || MODE==5){
    unsigned* lh2 = (unsigned*)smem4;       // alias dead tile buffer
    for(int x=tid;x<2048;x+=256) lh2[x]=0u;
    __syncthreads();
    unsigned m0, m1;
    if constexpr (MODE==4){ m0=sel[0]; m1=sel[1]; }
    else                  { m0=(sel[0]<<10)|sel[4]; m1=(sel[1]<<10)|sel[5]; }
    #pragma unroll
    for(int r=0;r<8;++r){
      #pragma unroll
      for(int c=0;c<8;++c){
        int col = (c<4) ? (tcl*4 + c) : (64 + tcl*4 + (c-4));
        int i = i0 + trw*8 + r, j = j0 + col;
        if(bi!=bj || i<j){
          float d = fmaxf(sqi[r]+sqj[c]-2.0f*acc[r][c], 0.0f);
          unsigned bits = __float_as_uint(d);
          unsigned key = (MODE==4) ? (bits>>20) : (bits>>10);
          unsigned bin = (MODE==4) ? ((bits>>10)&1023u) : (bits&1023u);
          if(key==m0)      atomicAdd(&lh2[bin], 1u);
          else if(key==m1) atomicAdd(&lh2[1024+bin], 1u);
        }
      }
    }
    __syncthreads();
    unsigned* hout = (MODE==4) ? hmid : hlow;
    for(int x=tid;x<2048;x+=256){ unsigned v=lh2[x]; if(v) atomicAdd(&hout[x], v); }
  } else {
    float sig = *sigp;
    float inv = 1.0f/sig;
    float k0=2.0f*inv, k1=inv, k2=0.5f*inv, k3=0.25f*inv, k4=0.125f*inv;
    double lsum = 0.0;
    #pragma unroll
    for(int r=0;r<8;++r){
      #pragma unroll
      for(int c=0;c<8;++c){
        int col = (c<4) ? (tcl*4 + c) : (64 + tcl*4 + (c-4));
        int i = i0 + trw*8 + r, j = j0 + col;
        if(bi!=bj || i<j){
          float d = fmaxf(sqi[r]+sqj[c]-2.0f*acc[r][c], 0.0f);
          float kv = expf(-d*k0)+expf(-d*k1)+expf(-d*k2)+expf(-d*k3)+expf(-d*k4);
          lsum += (double)kv;
        }
      }
    }
    for(int off=32; off; off>>=1) lsum += __shfl_down(lsum, off);
    double* redbuf = (double*)smem4;        // alias dead tile buffer
    if((tid&63)==0) redbuf[tid>>6] = lsum;
    __syncthreads();
    if(tid==0) blockSums[blockIdx.x] = (redbuf[0]+redbuf[1]+redbuf[2]+redbuf[3])*0.2; // /KERNEL_NUM
  }
}

// ---------------- streaming hierarchical hist over cached D ----------------
// LVL 0: match top-12, bin = bits[10:20)   LVL 1: match top-22, bin = bits[0:10)
template<int LVL>
__global__ __launch_bounds__(256) void hist_stream_k(const float* __restrict__ D, const unsigned* __restrict__ sel,
                                                     unsigned* __restrict__ hout){
  __shared__ unsigned lh[2048];
  int tid = threadIdx.x;
  for(int x=tid;x<2048;x+=256) lh[x]=0u;
  __syncthreads();
  unsigned m0, m1;
  if constexpr (LVL==0){ m0=sel[0]; m1=sel[1]; }
  else                 { m0=(sel[0]<<10)|sel[4]; m1=(sel[1]<<10)|sel[5]; }
  const float4* P = (const float4*)(D + (size_t)blockIdx.x*16384);
  #pragma unroll
  for(int k=0;k<16;++k){
    float4 v = P[tid + k*256];
    float vals[4] = {v.x, v.y, v.z, v.w};
    #pragma unroll
    for(int q=0;q<4;++q){
      unsigned bits = __float_as_uint(vals[q]);   // +inf sentinel never matches finite key
      unsigned key = (LVL==0) ? (bits>>20) : (bits>>10);
      unsigned bin = (LVL==0) ? ((bits>>10)&1023u) : (bits&1023u);
      if(key==m0)      atomicAdd(&lh[bin], 1u);
      else if(key==m1) atomicAdd(&lh[1024+bin], 1u);
    }
  }
  __syncthreads();
  for(int x=tid;x<2048;x+=256){ unsigned v=lh[x]; if(v) atomicAdd(&hout[x], v); }
}

// ---------------- streaming kernel sums over cached distances ----------------
__global__ __launch_bounds__(256) void ksum_k(const float* __restrict__ D, const float* __restrict__ sigp,
                                              double* __restrict__ blockSums){
  float sig = *sigp;
  float inv = 1.0f/sig;
  float k0=2.0f*inv, k1=inv, k2=0.5f*inv, k3=0.25f*inv, k4=0.125f*inv;
  const float4* P = (const float4*)(D + (size_t)blockIdx.x*16384);
  int tid = threadIdx.x;
  double lsum = 0.0;
  #pragma unroll
  for(int k=0;k<16;++k){
    float4 v = P[tid + k*256];
    float vals[4] = {v.x, v.y, v.z, v.w};
    #pragma unroll
    for(int q=0;q<4;++q){
      float d = vals[q];                   // +inf sentinel -> expf(-inf)=0 contributes nothing
      float kv = expf(-d*k0)+expf(-d*k1)+expf(-d*k2)+expf(-d*k3)+expf(-d*k4);
      lsum += (double)kv;
    }
  }
  for(int off=32; off; off>>=1) lsum += __shfl_down(lsum, off);
  __shared__ double redbuf[4];
  if((tid&63)==0) redbuf[tid>>6] = lsum;
  __syncthreads();
  if(tid==0) blockSums[blockIdx.x] = (redbuf[0]+redbuf[1]+redbuf[2]+redbuf[3])*0.2;
}

// ---------------- selection 1: find 12-bit bucket + in-bucket ranks ----------------
__global__ __launch_bounds__(256) void sel1_k(const unsigned* __restrict__ hist1, unsigned* __restrict__ sel){
  __shared__ unsigned part[256];
  int tid = threadIdx.x;
  unsigned s = 0;
  #pragma unroll
  for(int k=0;k<16;++k) s += hist1[tid*16+k];
  part[tid] = s;
  __syncthreads();
  if(tid==0){
    const unsigned ranks[2] = {R0, R1};
    unsigned segs[2], bases[2];
    unsigned cum = 0; int found = 0;
    for(int i=0; i<256 && found<2; ++i){
      unsigned nx = cum + part[i];
      while(found<2 && ranks[found] < nx){ segs[found]=i; bases[found]=cum; ++found; }
      cum = nx;
    }
    for(int tg=0; tg<2; ++tg){
      unsigned c2 = bases[tg];
      for(int b=segs[tg]*16;; ++b){
        unsigned nx = c2 + hist1[b];
        if(ranks[tg] < nx){ sel[tg]=(unsigned)b; sel[2+tg]=ranks[tg]-c2; break; }
        c2 = nx;
      }
    }
  }
}

// ---------------- selection B: 10-bit mid segment + residual rank ----------------
__global__ __launch_bounds__(1024) void selB_k(const unsigned* __restrict__ hmid, unsigned* __restrict__ sel){
  __shared__ unsigned buf[1024];
  __shared__ unsigned res[4];       // seg0, rem0, seg1, rem1
  int tid = threadIdx.x;
  for(int tgt=0; tgt<2; ++tgt){
    bool useA = (tgt==0) || (sel[1]==sel[0]);
    const unsigned* H = hmid + (useA ? 0 : 1024);
    unsigned rank = sel[2+tgt];
    buf[tid] = H[tid];
    __syncthreads();
    for(int off=1; off<1024; off<<=1){
      unsigned v = buf[tid];
      unsigned a = (tid>=off) ? buf[tid-off] : 0u;
      __syncthreads();
      buf[tid] = v + a;
      __syncthreads();
    }
    unsigned prev = tid ? buf[tid-1] : 0u;
    if(rank < buf[tid] && rank >= prev){ res[2*tgt]=(unsigned)tid; res[2*tgt+1]=rank-prev; }
    __syncthreads();
  }
  if(tid==0){ sel[4]=res[0]; sel[6]=res[1]; sel[5]=res[2]; sel[7]=res[3]; }
}

// ---------------- selection C: low 10 bits -> exact order stats -> sigma ----------------
__global__ __launch_bounds__(1024) void selC_k(const unsigned* __restrict__ hlow, const unsigned* __restrict__ sel,
                                               float* __restrict__ sigp){
  __shared__ unsigned buf[1024];
  __shared__ unsigned outbits[2];
  int tid = threadIdx.x;
  for(int tgt=0; tgt<2; ++tgt){
    bool useA = (tgt==0) || ((sel[1]==sel[0]) && (sel[5]==sel[4]));
    const unsigned* H = hlow + (useA ? 0 : 1024);
    unsigned rank = sel[6+tgt];
    buf[tid] = H[tid];
    __syncthreads();
    for(int off=1; off<1024; off<<=1){
      unsigned v = buf[tid];
      unsigned a = (tid>=off) ? buf[tid-off] : 0u;
      __syncthreads();
      buf[tid] = v + a;
      __syncthreads();
    }
    unsigned prev = tid ? buf[tid-1] : 0u;
    if(rank < buf[tid] && rank >= prev){
      outbits[tgt] = (sel[tgt]<<20) | (sel[4+tgt]<<10) | (unsigned)tid;
    }
    __syncthreads();
  }
  if(tid==0){
    float v0 = __uint_as_float(outbits[0]);
    float v1 = __uint_as_float(outbits[1]);
    *sigp = 0.5f*(v0+v1);
  }
}

// ---------------- final reduction: MMD ----------------
__global__ __launch_bounds__(256) void final_k(const double* __restrict__ blockSums, float* __restrict__ out){
  __shared__ double cls[3][256];
  int tid = threadIdx.x;
  double l0=0, l1=0, l2=0;
  for(int b=tid; b<NBLK; b+=256){
    int t=b, bi=0;
    while(t >= NTILE - bi){ t -= NTILE - bi; ++bi; }
    int bj = bi + t;
    double v = blockSums[b];
    if(bj < 32) l0 += v;          // XX
    else if(bi >= 32) l2 += v;    // YY
    else l1 += v;                 // XY
  }
  cls[0][tid]=l0; cls[1][tid]=l1; cls[2][tid]=l2;
  __syncthreads();
  for(int off=128; off; off>>=1){
    if(tid<off){ cls[0][tid]+=cls[0][tid+off]; cls[1][tid]+=cls[1][tid+off]; cls[2][tid]+=cls[2][tid+off]; }
    __syncthreads();
  }
  if(tid==0){
    double sxx=cls[0][0], sxy=cls[1][0], syy=cls[2][0];
    double mxx = (2.0*sxx)/((double)NN*(NN-1));   // trace cancels: K(0)=1 per row
    double myy = (2.0*syy)/((double)NN*(NN-1));
    double mxy = sxy/((double)NN*(double)NN);
    double r = mxx + myy - 2.0*mxy;
    out[0] = fmaxf((float)r, 0.0f);
  }
}

extern "C" void kernel_launch(void* const* d_in, const int* in_sizes, int n_in,
                              void* d_out, int out_size, void* d_ws, size_t ws_size,
                              hipStream_t stream){
  (void)in_sizes; (void)n_in; (void)out_size;
  const float* featS = (const float*)d_in[0];
  const float* featT = (const float*)d_in[1];
  const int*   eiS   = (const int*)d_in[2];
  const int*   eiT   = (const int*)d_in[3];
  char* ws = (char*)d_ws;
  unsigned* Mb    = (unsigned*)(ws + OFF_MB);
  unsigned* hist1 = (unsigned*)(ws + OFF_H1);
  unsigned* hmid  = (unsigned*)(ws + OFF_HMID);
  unsigned* hlow  = (unsigned*)(ws + OFF_HLOW);
  int*      degc  = (int*)(ws + OFF_DEG);
  int*      tric  = (int*)(ws + OFF_TRI);
  float*    XYT   = (float*)(ws + OFF_XYT);
  float*    sq    = (float*)(ws + OFF_SQ);
  double*   bsums = (double*)(ws + OFF_BS);
  unsigned* sel   = (unsigned*)(ws + OFF_SEL);
  float*    sigp  = (float*)(ws + OFF_SIG);
  float*    Dbuf  = (float*)(ws + OFF_D);
  float*    out   = (float*)d_out;

  const bool cached = (ws_size >= WS_CACHED);   // launch-constant -> graph-capture safe

  hipMemsetAsync(ws, 0, (size_t)ZERO_BYTES, stream);

  build_k   <<<512, 256, 0, stream>>>(eiS, eiT, Mb, degc);
  tri_k     <<<256, 512, 0, stream>>>(eiS, eiT, Mb, tric);
  finalize_k<<<NTOT, 64, 0, stream>>>(featS, featT, Mb, degc, tric, XYT, sq);

  if(cached){
    pair_k<3>       <<<NBLK, 256, 0, stream>>>(XYT, sq, hist1, hmid, hlow, sel, sigp, bsums, Dbuf);
    sel1_k          <<<1, 256, 0, stream>>>(hist1, sel);
    hist_stream_k<0><<<NBLK, 256, 0, stream>>>(Dbuf, sel, hmid);
    selB_k          <<<1, 1024, 0, stream>>>(hmid, sel);
    hist_stream_k<1><<<NBLK, 256, 0, stream>>>(Dbuf, sel, hlow);
    selC_k          <<<1, 1024, 0, stream>>>(hlow, sel, sigp);
    ksum_k          <<<NBLK, 256, 0, stream>>>(Dbuf, sigp, bsums);
  } else {
    pair_k<0>       <<<NBLK, 256, 0, stream>>>(XYT, sq, hist1, hmid, hlow, sel, sigp, bsums, Dbuf);
    sel1_k          <<<1, 256, 0, stream>>>(hist1, sel);
    pair_k<4>       <<<NBLK, 256, 0, stream>>>(XYT, sq, hist1, hmid, hlow, sel, sigp, bsums, Dbuf);
    selB_k          <<<1, 1024, 0, stream>>>(hmid, sel);
    pair_k<5>       <<<NBLK, 256, 0, stream>>>(XYT, sq, hist1, hmid, hlow, sel, sigp, bsums, Dbuf);
    selC_k          <<<1, 1024, 0, stream>>>(hlow, sel, sigp);
    pair_k<2>       <<<NBLK, 256, 0, stream>>>(XYT, sq, hist1, hmid, hlow, sel, sigp, bsums, Dbuf);
  }

  final_k  <<<1, 256, 0, stream>>>(bsums, out);
}